// Round 3
// baseline (10800.094 us; speedup 1.0000x reference)
//
#include <hip/hip_runtime.h>
#include <math.h>

// TransformerCell recurrence, 4 phases/step, 64 main blocks.
//   A : assemble z_{t-1} = z_{t-2} + sum_32 zpart + m_out_b (redundant, in-reg),
//       write Z[t-1] (own 16 cols), append d_{t-1}=B z, U_{t-1}=W~ z (16 rows/block,
//       B/W~ in registers), recompute logits lg[i]=dC[i].z for i<=t-2 (1 row/wave),
//       partials of logit_{t-1} -> lgp[bid].
//   SM: softmax (redundant per block; zero rows add (257-t)exp(-m) to denom),
//       f1[16 cols of block] = lrelu(sum_i a_i uC[i][col] + m_in_b).
//   C : f2[16 rows] = lrelu(m_h0_w f1 + b).
//   DE: 32 worker blocks: f3[32 cols] = lrelu(m_h1_w[rows] f2 + b);
//       zpart[b] = m_out_w[:, 32b..32b+32) . f3  (1024-vector, plain stores).
// Barrier v3: arrival fetch_add to 1-of-8 group counters; every block's wave0
// polls all 8 counters with an 8-lane vector atomic load; exit when all >=
// 8*(k+1). Monotonic, no release stage, ~1 LLC RTT + poll.
// Coherence rule: per-step-rewritten buffers (lg/lgp/f1/f2/zpart) via relaxed
// agent-scope atomics (LLC). Write-once data (dC/uC rows, Z rows) written by
// astore, read later by NORMAL cached loads (lines never normal-read before
// their write). Weights: normal cached loads (L2-resident, never invalidated).

#define NTHR 256
#define NBLK 256
#define NMAIN 64
#define NDE 32

// float offsets in ws
#define OFF_B   2048
#define OFF_W   (OFF_B + 1048576)
#define OFF_D   OFF_B                  /* dC[257][1024], aliases B (B dead after reg-load) */
#define OFF_U   (OFF_B + 263168)       /* uC[257][1024] */
#define OFF_ZP  (OFF_B + 526336)       /* zpart[32][1024] */
#define OFF_LG  (OFF_W + 1048576)      /* 257 logits */
#define OFF_LGP (OFF_LG + 320)         /* 64 partials */
#define OFF_F1  (OFF_LGP + 64)
#define OFF_F2  (OFF_F1 + 1024)
#define OFF_F3  (OFF_F2 + 1024)        /* prologue scratch */

__device__ __forceinline__ float aload(const float* p) {
  return __hip_atomic_load((float*)p, __ATOMIC_RELAXED, __HIP_MEMORY_SCOPE_AGENT);
}
__device__ __forceinline__ void astore(float* p, float v) {
  __hip_atomic_store(p, v, __ATOMIC_RELAXED, __HIP_MEMORY_SCOPE_AGENT);
}
__device__ __forceinline__ float2 aload2(const float* p) {
  double d = __hip_atomic_load((double*)p, __ATOMIC_RELAXED, __HIP_MEMORY_SCOPE_AGENT);
  return __builtin_bit_cast(float2, d);
}
__device__ __forceinline__ void astore2(float* p, float2 v) {
  __hip_atomic_store((double*)p, __builtin_bit_cast(double, v), __ATOMIC_RELAXED, __HIP_MEMORY_SCOPE_AGENT);
}
__device__ __forceinline__ int aloadI(const int* p) {
  return __hip_atomic_load((int*)p, __ATOMIC_RELAXED, __HIP_MEMORY_SCOPE_AGENT);
}
__device__ __forceinline__ int afaddI(int* p) {
  return __hip_atomic_fetch_add(p, 1, __ATOMIC_RELAXED, __HIP_MEMORY_SCOPE_AGENT);
}

__device__ __forceinline__ float wred(float v) {
#pragma unroll
  for (int o = 1; o < 64; o <<= 1) v += __shfl_xor(v, o, 64);
  return v;
}
__device__ __forceinline__ void wred2(float& a, float& b) {
#pragma unroll
  for (int o = 1; o < 64; o <<= 1) { a += __shfl_xor(a, o, 64); b += __shfl_xor(b, o, 64); }
}

// lite barrier: 64 blocks, 8 group counters at bar[0..127]
__device__ __forceinline__ void barlite(int* bar, int k, int bid, int lane) {
  asm volatile("" ::: "memory");
  __builtin_amdgcn_s_waitcnt(0);
  __syncthreads();
  if (threadIdx.x < 64) {
    if (lane == 0) afaddI(&bar[(bid >> 3) * 16]);
    const int target = (k + 1) * 8;
    for (;;) {
      int v = (lane < 8) ? aloadI(&bar[lane * 16]) : 0x7fffffff;
      if (__all(v >= target)) break;
      __builtin_amdgcn_s_sleep(1);
    }
  }
  __syncthreads();
  asm volatile("" ::: "memory");
}
// full barrier: 256 blocks, 32 group counters at bar[256..767]
__device__ __forceinline__ void barfull(int* bar, int k, int bid, int lane) {
  asm volatile("" ::: "memory");
  __builtin_amdgcn_s_waitcnt(0);
  __syncthreads();
  if (threadIdx.x < 64) {
    if (lane == 0) afaddI(&bar[256 + (bid >> 3) * 16]);
    const int target = (k + 1) * 8;
    for (;;) {
      int v = (lane < 32) ? aloadI(&bar[256 + lane * 16]) : 0x7fffffff;
      if (__all(v >= target)) break;
      __builtin_amdgcn_s_sleep(1);
    }
  }
  __syncthreads();
  asm volatile("" ::: "memory");
}

// prologue matvec: 1 row/wave (r = 4*bid+wave), K=1024
template<int ACT>
__device__ __forceinline__ void mlrow1(const float* __restrict__ Wm, const float* __restrict__ bv,
                                       const float* xa, float* out, int bid, int wave, int lane) {
  float2 x[8];
#pragma unroll
  for (int i = 0; i < 8; ++i) x[i] = aload2(xa + 2 * lane + 128 * i);
  int r = 4 * bid + wave;
  const float* w = Wm + (size_t)r * 1024;
  float acc = 0.f;
#pragma unroll
  for (int i = 0; i < 8; ++i) {
    float2 wf = *(const float2*)(w + 2 * lane + 128 * i);
    acc = fmaf(wf.x, x[i].x, acc); acc = fmaf(wf.y, x[i].y, acc);
  }
  acc = wred(acc);
  if (lane == 0) {
    acc += bv[r];
    if (ACT) acc = acc > 0.f ? acc : 0.01f * acc;
    astore(out + r, acc);
  }
}

__global__ void __launch_bounds__(NTHR, 1) tcell(
    const float* __restrict__ mu, const float* __restrict__ z0,
    const float* __restrict__ W1, const float* __restrict__ W2, const float* __restrict__ W3,
    const float* __restrict__ p_in_w, const float* __restrict__ p_in_b,
    const float* __restrict__ p_h0_w, const float* __restrict__ p_h0_b,
    const float* __restrict__ p_h1_w, const float* __restrict__ p_h1_b,
    const float* __restrict__ p_out_w, const float* __restrict__ p_out_b,
    const float* __restrict__ m_in_w, const float* __restrict__ m_in_b,
    const float* __restrict__ m_h0_w, const float* __restrict__ m_h0_b,
    const float* __restrict__ m_h1_w, const float* __restrict__ m_h1_b,
    const float* __restrict__ m_out_w, const float* __restrict__ m_out_b,
    float* __restrict__ Z, float* __restrict__ ws) {
  const int tid = threadIdx.x;
  const int bid = blockIdx.x;
  const int lane = tid & 63;
  const int wave = tid >> 6;

  int* bar = (int*)ws;
  float* dC = ws + OFF_D;
  float* uC = ws + OFF_U;
  float* zpart = ws + OFF_ZP;
  float* lg = ws + OFF_LG;
  float* lgp = ws + OFF_LGP;
  float* f1 = ws + OFF_F1;
  float* f2 = ws + OFF_F2;
  float* f3 = ws + OFF_F3;
  const float* dCn = dC;   // normal-load views
  const float* uCn = uC;

  __shared__ float sZ[1024];
  __shared__ float sA[256];
  __shared__ float sP[16][17];
  __shared__ float sF3[32];
  __shared__ float shM[4];
  __shared__ float shP[4];

  // ---- P0: B = W1@W2, W~ = m_in_w@W3 (4 rows/block, 1/wave); p_in layer
  {
    int r = 4 * bid + wave;
    const float* w1r = W1 + (size_t)r * 512;
    const float* mir = m_in_w + (size_t)r * 512;
    float2 aB[8], aW[8];
#pragma unroll
    for (int i = 0; i < 8; ++i) { aB[i] = make_float2(0.f, 0.f); aW[i] = make_float2(0.f, 0.f); }
    for (int k = 0; k < 512; ++k) {
      float w1 = w1r[k], mi = mir[k];
      const float* w2r = W2 + (size_t)k * 1024 + 2 * lane;
      const float* w3r = W3 + (size_t)k * 1024 + 2 * lane;
#pragma unroll
      for (int i = 0; i < 8; ++i) {
        float2 a = *(const float2*)(w2r + 128 * i);
        float2 b = *(const float2*)(w3r + 128 * i);
        aB[i].x = fmaf(w1, a.x, aB[i].x); aB[i].y = fmaf(w1, a.y, aB[i].y);
        aW[i].x = fmaf(mi, b.x, aW[i].x); aW[i].y = fmaf(mi, b.y, aW[i].y);
      }
    }
#pragma unroll
    for (int i = 0; i < 8; ++i) {
      astore2(ws + OFF_B + (size_t)r * 1024 + 2 * lane + 128 * i, aB[i]);
      astore2(ws + OFF_W + (size_t)r * 1024 + 2 * lane + 128 * i, aW[i]);
    }
    float acc = p_in_w[(size_t)r * 64 + lane] * mu[lane];
    acc = wred(acc);
    if (lane == 0) { acc += p_in_b[r]; acc = acc > 0.f ? acc : 0.01f * acc; astore(f1 + r, acc); }
  }
  barfull(bar, 0, bid, lane);

  // ---- P1: p_h0; main blocks load B/W~ rows into registers
  float2 rB[4][8], rW[4][8];
  if (bid < NMAIN) {
#pragma unroll
    for (int j = 0; j < 4; ++j) {
      int r = 16 * bid + 4 * wave + j;
#pragma unroll
      for (int i = 0; i < 8; ++i) {
        rB[j][i] = aload2(ws + OFF_B + (size_t)r * 1024 + 2 * lane + 128 * i);
        rW[j][i] = aload2(ws + OFF_W + (size_t)r * 1024 + 2 * lane + 128 * i);
      }
    }
  }
  mlrow1<1>(p_h0_w, p_h0_b, f1, f2, bid, wave, lane);
  barfull(bar, 1, bid, lane);
  mlrow1<1>(p_h1_w, p_h1_b, f2, f3, bid, wave, lane);
  barfull(bar, 2, bid, lane);
  mlrow1<0>(p_out_w, p_out_b, f3, Z, bid, wave, lane);       // Z[0] = z_minus
  if (bid < 4) astore(Z + 1024 + bid * 256 + tid, z0[bid * 256 + tid]);  // Z[1] = z_0
  barfull(bar, 3, bid, lane);

  if (bid >= NMAIN) return;

  // persistent per-thread state
  float4 zreg = *(const float4*)(z0 + 4 * tid);              // z_1
  float4 bias4 = *(const float4*)(m_out_b + 4 * tid);

  // ---- P4: append row 0 (d_0, U_0 from Z[0], normal loads of fresh astore'd line)
  {
    float2 zp[8];
#pragma unroll
    for (int i = 0; i < 8; ++i) zp[i] = *(const float2*)(Z + 2 * lane + 128 * i);
#pragma unroll
    for (int j = 0; j < 4; ++j) {
      int r = 16 * bid + 4 * wave + j;
      float aD = 0.f, aU = 0.f;
#pragma unroll
      for (int i = 0; i < 8; ++i) {
        aD = fmaf(rB[j][i].x, zp[i].x, aD); aD = fmaf(rB[j][i].y, zp[i].y, aD);
        aU = fmaf(rW[j][i].x, zp[i].x, aU); aU = fmaf(rW[j][i].y, zp[i].y, aU);
      }
      wred2(aD, aU);
      if (lane == 0) { astore(dC + r, aD); astore(uC + r, aU); }
    }
  }
  int lk = 0;
  barlite(bar, lk++, bid, lane);

  // ---- main recurrence
  for (int t = 2; t <= 256; ++t) {
    // ---------- Phase A ----------
    {
      if (t > 2) {
        float4 s = zreg;
#pragma unroll 8
        for (int p = 0; p < 32; ++p) {
          float2 a = aload2(zpart + (size_t)p * 1024 + 4 * tid);
          float2 b = aload2(zpart + (size_t)p * 1024 + 4 * tid + 2);
          s.x += a.x; s.y += a.y; s.z += b.x; s.w += b.y;
        }
        s.x += bias4.x; s.y += bias4.y; s.z += bias4.z; s.w += bias4.w;
        zreg = s;
      }
      if ((tid >> 2) == bid) {   // own 16 cols of Z[t-1]
        astore2(Z + (size_t)(t - 1) * 1024 + 4 * tid, make_float2(zreg.x, zreg.y));
        astore2(Z + (size_t)(t - 1) * 1024 + 4 * tid + 2, make_float2(zreg.z, zreg.w));
      }
      *(float4*)(sZ + 4 * tid) = zreg;
      __syncthreads();
      float2 zp[8];
#pragma unroll
      for (int i = 0; i < 8; ++i) zp[i] = *(const float2*)(sZ + 2 * lane + 128 * i);
      // append d/U row t-1
      float pl = 0.f;
      float* dRow = dC + (size_t)(t - 1) * 1024;
      float* uRow = uC + (size_t)(t - 1) * 1024;
#pragma unroll
      for (int j = 0; j < 4; ++j) {
        int r = 16 * bid + 4 * wave + j;
        float aD = 0.f, aU = 0.f;
#pragma unroll
        for (int i = 0; i < 8; ++i) {
          aD = fmaf(rB[j][i].x, zp[i].x, aD); aD = fmaf(rB[j][i].y, zp[i].y, aD);
          aU = fmaf(rW[j][i].x, zp[i].x, aU); aU = fmaf(rW[j][i].y, zp[i].y, aU);
        }
        wred2(aD, aU);
        if (lane == 0) {
          astore(dRow + r, aD); astore(uRow + r, aU);
          pl = fmaf(aD, sZ[r], pl);
        }
      }
      if (lane == 0) shP[wave] = pl;
      // logits for old rows: 1 row/wave, i = bid + 64*wave
      int i0 = bid + 64 * wave;
      if (i0 <= t - 2) {
        const float* dr = dCn + (size_t)i0 * 1024;
        float acc = 0.f;
#pragma unroll
        for (int i = 0; i < 8; ++i) {
          float2 df = *(const float2*)(dr + 2 * lane + 128 * i);
          acc = fmaf(df.x, zp[i].x, acc); acc = fmaf(df.y, zp[i].y, acc);
        }
        acc = wred(acc);
        if (lane == 0) astore(lg + i0, acc);
      }
      __syncthreads();
      if (tid == 0) astore(lgp + bid, shP[0] + shP[1] + shP[2] + shP[3]);
    }
    barlite(bar, lk++, bid, lane);

    // ---------- Phase SM ----------
    {
      float s = aload(lgp + lane);           // each wave reduces all 64 partials
      s = wred(s);
      float l = -1e30f;
      if (tid <= t - 2) l = aload(lg + tid) * 0.03125f;
      if (tid == t - 1) l = s * 0.03125f;
      float mx = l;
#pragma unroll
      for (int o = 1; o < 64; o <<= 1) mx = fmaxf(mx, __shfl_xor(mx, o, 64));
      if (lane == 0) shM[wave] = mx;
      __syncthreads();
      float m = fmaxf(fmaxf(fmaxf(shM[0], shM[1]), fmaxf(shM[2], shM[3])), 0.f);
      float e = (tid <= t - 1) ? expf(l - m) : 0.f;
      float es = wred(e);
      __syncthreads();
      if (lane == 0) shM[wave] = es;
      __syncthreads();
      float den = shM[0] + shM[1] + shM[2] + shM[3] + (float)(257 - t) * expf(-m);
      sA[tid] = e / den;
      __syncthreads();
      // f1 cols [16*bid .. 16*bid+16): 16 i-chunks x 16 cols
      int c = tid & 15, ic = tid >> 4;
      int col = 16 * bid + c;
      float acc = 0.f;
      for (int j = 0; j < 16; ++j) {
        int i = ic + 16 * j;
        if (i <= t - 1) acc = fmaf(sA[i], uCn[(size_t)i * 1024 + col], acc);
      }
      sP[ic][c] = acc;
      __syncthreads();
      if (tid < 16) {
        float v = 0.f;
#pragma unroll
        for (int q = 0; q < 16; ++q) v += sP[q][tid];
        v += m_in_b[16 * bid + tid];
        v = v > 0.f ? v : 0.01f * v;
        astore(f1 + 16 * bid + tid, v);
      }
    }
    barlite(bar, lk++, bid, lane);

    // ---------- Phase C: f2 = lrelu(m_h0_w f1 + b), 16 rows/block ----------
    {
      float2 x[8];
#pragma unroll
      for (int i = 0; i < 8; ++i) x[i] = aload2(f1 + 2 * lane + 128 * i);
#pragma unroll
      for (int j = 0; j < 4; ++j) {
        int r = 16 * bid + 4 * wave + j;
        const float* w = m_h0_w + (size_t)r * 1024;
        float acc = 0.f;
#pragma unroll
        for (int i = 0; i < 8; ++i) {
          float2 wf = *(const float2*)(w + 2 * lane + 128 * i);
          acc = fmaf(wf.x, x[i].x, acc); acc = fmaf(wf.y, x[i].y, acc);
        }
        acc = wred(acc);
        if (lane == 0) {
          acc += m_h0_b[r];
          acc = acc > 0.f ? acc : 0.01f * acc;
          astore(f2 + r, acc);
        }
      }
    }
    barlite(bar, lk++, bid, lane);

    // ---------- Phase DE: f3 cols + zpart partials (32 worker blocks) ----------
    if (bid < NDE) {
      float2 x[8];
#pragma unroll
      for (int i = 0; i < 8; ++i) x[i] = aload2(f2 + 2 * lane + 128 * i);
#pragma unroll
      for (int j = 0; j < 8; ++j) {
        int cc = 8 * wave + j;             // 0..31 local col
        int r = 32 * bid + cc;             // f3 index / H1 row
        const float* w = m_h1_w + (size_t)r * 1024;
        float acc = 0.f;
#pragma unroll
        for (int i = 0; i < 8; ++i) {
          float2 wf = *(const float2*)(w + 2 * lane + 128 * i);
          acc = fmaf(wf.x, x[i].x, acc); acc = fmaf(wf.y, x[i].y, acc);
        }
        acc = wred(acc);
        if (lane == 0) {
          acc += m_h1_b[r];
          sF3[cc] = acc > 0.f ? acc : 0.01f * acc;
        }
      }
      __syncthreads();
#pragma unroll
      for (int u = 0; u < 4; ++u) {
        int r = tid + 256 * u;
        const float* w = m_out_w + (size_t)r * 1024 + 32 * bid;
        float acc = 0.f;
#pragma unroll
        for (int k = 0; k < 32; k += 4) {
          float4 wf = *(const float4*)(w + k);
          acc = fmaf(wf.x, sF3[k], acc);     acc = fmaf(wf.y, sF3[k + 1], acc);
          acc = fmaf(wf.z, sF3[k + 2], acc); acc = fmaf(wf.w, sF3[k + 3], acc);
        }
        astore(zpart + (size_t)bid * 1024 + r, acc);
      }
    }
    barlite(bar, lk++, bid, lane);
  }

  // ---- epilogue: assemble z_256, write Z[256]
  {
    float4 s = zreg;
#pragma unroll 8
    for (int p = 0; p < 32; ++p) {
      float2 a = aload2(zpart + (size_t)p * 1024 + 4 * tid);
      float2 b = aload2(zpart + (size_t)p * 1024 + 4 * tid + 2);
      s.x += a.x; s.y += a.y; s.z += b.x; s.w += b.y;
    }
    s.x += bias4.x; s.y += bias4.y; s.z += bias4.z; s.w += bias4.w;
    if ((tid >> 2) == bid) {
      astore2(Z + (size_t)256 * 1024 + 4 * tid, make_float2(s.x, s.y));
      astore2(Z + (size_t)256 * 1024 + 4 * tid + 2, make_float2(s.z, s.w));
    }
  }
}

extern "C" void kernel_launch(void* const* d_in, const int* in_sizes, int n_in,
                              void* d_out, int out_size, void* d_ws, size_t ws_size,
                              hipStream_t stream) {
  (void)in_sizes; (void)n_in; (void)out_size; (void)ws_size;
  hipMemsetAsync(d_ws, 0, 8192, stream);  // barrier counters
  tcell<<<dim3(NBLK), dim3(NTHR), 0, stream>>>(
      (const float*)d_in[0],  (const float*)d_in[1],
      (const float*)d_in[2],  (const float*)d_in[3],  (const float*)d_in[4],
      (const float*)d_in[5],  (const float*)d_in[6],
      (const float*)d_in[7],  (const float*)d_in[8],
      (const float*)d_in[9],  (const float*)d_in[10],
      (const float*)d_in[11], (const float*)d_in[12],
      (const float*)d_in[13], (const float*)d_in[14],
      (const float*)d_in[15], (const float*)d_in[16],
      (const float*)d_in[17], (const float*)d_in[18],
      (const float*)d_in[19], (const float*)d_in[20],
      (float*)d_out, (float*)d_ws);
}

// Round 4
// 9348.579 us; speedup vs baseline: 1.1553x; 1.1553x over previous
//
#include <hip/hip_runtime.h>
#include <math.h>

// TransformerCell recurrence, 4 phases/step, 64 blocks x 1024 threads (16 waves).
// See round notes: dataflow done-counter sync, B=W1@W2 / W~=m_in_w@W3 in regs,
// transposed zpT partials, per-block fixed L1-resident row sets.

#define NTHR 1024
#define NBLK 64

// float offsets in ws
#define OFF_DC  1024          /* dC[257][1024] */
#define OFF_UC  264192        /* uC[257][1024] */
#define OFF_ZPT 527360        /* zpT[1024][32] */
#define OFF_LG  560128        /* 256 */
#define OFF_LGP 560384        /* 64 */
#define OFF_F1  560448        /* 1024 */
#define OFF_F2  561472        /* 1024 */
#define OFF_F3  562496        /* 1024 (prologue) */

// counter bases (int index), 8 lines (x16 ints) each
#define CNT_A   0
#define CNT_SM  128
#define CNT_C   256
#define CNT_DE  384
#define CNT_P0  512
#define CNT_P1  640
#define CNT_P2  768
#define CNT_P3  896

__device__ __forceinline__ float aload(const float* p) {
  return __hip_atomic_load((float*)p, __ATOMIC_RELAXED, __HIP_MEMORY_SCOPE_AGENT);
}
__device__ __forceinline__ void astore(float* p, float v) {
  __hip_atomic_store(p, v, __ATOMIC_RELAXED, __HIP_MEMORY_SCOPE_AGENT);
}
__device__ __forceinline__ float2 aload2(const float* p) {
  double d = __hip_atomic_load((double*)p, __ATOMIC_RELAXED, __HIP_MEMORY_SCOPE_AGENT);
  return __builtin_bit_cast(float2, d);
}
__device__ __forceinline__ int aloadI(const int* p) {
  return __hip_atomic_load((int*)p, __ATOMIC_RELAXED, __HIP_MEMORY_SCOPE_AGENT);
}
__device__ __forceinline__ int afaddI(int* p) {
  return __hip_atomic_fetch_add(p, 1, __ATOMIC_RELAXED, __HIP_MEMORY_SCOPE_AGENT);
}

__device__ __forceinline__ float wred(float v) {
#pragma unroll
  for (int o = 1; o < 64; o <<= 1) v += __shfl_xor(v, o, 64);
  return v;
}
__device__ __forceinline__ void wred2(float& a, float& b) {
#pragma unroll
  for (int o = 1; o < 64; o <<= 1) { a += __shfl_xor(a, o, 64); b += __shfl_xor(b, o, 64); }
}
__device__ __forceinline__ float lrelu(float x) { return x > 0.f ? x : 0.01f * x; }

__device__ __forceinline__ void waitc(int* base, int tgt, int tid, int lane) {
  if (tid < 64) {
    for (;;) {
      int v = (lane < 8) ? aloadI(base + lane * 16) : 0x7fffffff;
      if (__all(v >= tgt)) break;
      __builtin_amdgcn_s_sleep(1);
    }
  }
  __syncthreads();
  asm volatile("" ::: "memory");
}
__device__ __forceinline__ void incc(int* base, int bid, int tid) {
  asm volatile("" ::: "memory");
  __builtin_amdgcn_s_waitcnt(0);
  __syncthreads();
  if (tid == 0) afaddI(base + (bid & 7) * 16);
}

__global__ void __launch_bounds__(NTHR, 4) tcell(
    const float* __restrict__ mu, const float* __restrict__ z0,
    const float* __restrict__ W1, const float* __restrict__ W2, const float* __restrict__ W3,
    const float* __restrict__ p_in_w, const float* __restrict__ p_in_b,
    const float* __restrict__ p_h0_w, const float* __restrict__ p_h0_b,
    const float* __restrict__ p_h1_w, const float* __restrict__ p_h1_b,
    const float* __restrict__ p_out_w, const float* __restrict__ p_out_b,
    const float* __restrict__ m_in_w, const float* __restrict__ m_in_b,
    const float* __restrict__ m_h0_w, const float* __restrict__ m_h0_b,
    const float* __restrict__ m_h1_w, const float* __restrict__ m_h1_b,
    const float* __restrict__ m_out_w, const float* __restrict__ m_out_b,
    float* __restrict__ Z, float* __restrict__ ws) {
  const int tid = threadIdx.x;
  const int bid = blockIdx.x;
  const int lane = tid & 63;
  const int wave = tid >> 6;

  int* bar = (int*)ws;
  float* dC = ws + OFF_DC;
  float* uC = ws + OFF_UC;
  float* zpT = ws + OFF_ZPT;
  float* lg = ws + OFF_LG;
  float* lgp = ws + OFF_LGP;
  float* f1 = ws + OFF_F1;
  float* f2 = ws + OFF_F2;
  float* f3p = ws + OFF_F3;
  const float* dCn = dC;
  const float* uCn = uC;

  __shared__ float sZ[1024];
  __shared__ float sX[1024];
  __shared__ float sRed[8][1024];
  __shared__ float sA[256];
  __shared__ float sP[64][16];
  __shared__ float sQ[16][16];
  __shared__ float sF3[32];
  __shared__ float shP[16];
  __shared__ float shM[16];
  __shared__ float shS[16];
  __shared__ float shm0_;

  // ---- P0: accB/accW = own 16 rows of B=W1@W2, W~=m_in_w@W3; p_in layer
  float accB[16], accW[16];
#pragma unroll
  for (int j = 0; j < 16; ++j) { accB[j] = 0.f; accW[j] = 0.f; }
  {
    const float* __restrict__ w1b = W1 + (size_t)(16 * bid) * 512;
    const float* __restrict__ mib = m_in_w + (size_t)(16 * bid) * 512;
    for (int k0 = 0; k0 < 512; k0 += 8) {
      float x2[8], x3[8];
#pragma unroll
      for (int u = 0; u < 8; ++u) {
        x2[u] = W2[(size_t)(k0 + u) * 1024 + tid];
        x3[u] = W3[(size_t)(k0 + u) * 1024 + tid];
      }
#pragma unroll
      for (int j = 0; j < 16; ++j) {
        const float* __restrict__ wr = w1b + (size_t)j * 512 + k0;
        const float* __restrict__ mr = mib + (size_t)j * 512 + k0;
#pragma unroll
        for (int u = 0; u < 8; ++u) {
          accB[j] = fmaf(wr[u], x2[u], accB[j]);
          accW[j] = fmaf(mr[u], x3[u], accW[j]);
        }
      }
    }
    int r = 16 * bid + wave;
    float acc = p_in_w[(size_t)r * 64 + lane] * mu[lane];
    acc = wred(acc);
    if (lane == 0) astore(f1 + r, lrelu(acc + p_in_b[r]));
  }
  // redistribute: accB/accW (thread=col) -> rB/rW (wave=row, lane-sliced)
  float rB[16], rW[16];
#pragma unroll
  for (int half = 0; half < 2; ++half) {
    __syncthreads();
#pragma unroll
    for (int j = 0; j < 8; ++j) sRed[j][tid] = accB[8 * half + j];
    __syncthreads();
    if ((wave >> 3) == half) {
      int w8 = wave & 7;
#pragma unroll
      for (int q = 0; q < 16; ++q) rB[q] = sRed[w8][lane + 64 * q];
    }
  }
#pragma unroll
  for (int half = 0; half < 2; ++half) {
    __syncthreads();
#pragma unroll
    for (int j = 0; j < 8; ++j) sRed[j][tid] = accW[8 * half + j];
    __syncthreads();
    if ((wave >> 3) == half) {
      int w8 = wave & 7;
#pragma unroll
      for (int q = 0; q < 16; ++q) rW[q] = sRed[w8][lane + 64 * q];
    }
  }
  incc(bar + CNT_P0, bid, tid);
  waitc(bar + CNT_P0, 8, tid, lane);

  // ---- P1: f2 = lrelu(p_h0_w f1 + b)
  sX[tid] = aload(f1 + tid);
  __syncthreads();
  {
    int r = 16 * bid + wave;
    const float* w = p_h0_w + (size_t)r * 1024;
    float acc = 0.f;
#pragma unroll
    for (int q = 0; q < 16; ++q) acc = fmaf(w[lane + 64 * q], sX[lane + 64 * q], acc);
    acc = wred(acc);
    if (lane == 0) astore(f2 + r, lrelu(acc + p_h0_b[r]));
  }
  incc(bar + CNT_P1, bid, tid);
  waitc(bar + CNT_P1, 8, tid, lane);

  // ---- P2: f3p = lrelu(p_h1_w f2 + b)
  sX[tid] = aload(f2 + tid);
  __syncthreads();
  {
    int r = 16 * bid + wave;
    const float* w = p_h1_w + (size_t)r * 1024;
    float acc = 0.f;
#pragma unroll
    for (int q = 0; q < 16; ++q) acc = fmaf(w[lane + 64 * q], sX[lane + 64 * q], acc);
    acc = wred(acc);
    if (lane == 0) astore(f3p + r, lrelu(acc + p_h1_b[r]));
  }
  incc(bar + CNT_P2, bid, tid);
  waitc(bar + CNT_P2, 8, tid, lane);

  // ---- P3: Z[0] = p_out_w f3p + b;  Z[1] = z0
  sX[tid] = aload(f3p + tid);
  __syncthreads();
  {
    int r = 16 * bid + wave;
    const float* w = p_out_w + (size_t)r * 1024;
    float acc = 0.f;
#pragma unroll
    for (int q = 0; q < 16; ++q) acc = fmaf(w[lane + 64 * q], sX[lane + 64 * q], acc);
    acc = wred(acc);
    if (lane == 0) astore(Z + r, acc + p_out_b[r]);
  }
  if (bid == 0) astore(Z + 1024 + tid, z0[tid]);
  incc(bar + CNT_P3, bid, tid);
  waitc(bar + CNT_P3, 8, tid, lane);

  // ---- P4: append row 0
  sZ[tid] = aload(Z + tid);
  __syncthreads();
  {
    int r = 16 * bid + wave;
    float aD = 0.f, aU = 0.f;
#pragma unroll
    for (int q = 0; q < 16; ++q) {
      float zv = sZ[lane + 64 * q];
      aD = fmaf(rB[q], zv, aD);
      aU = fmaf(rW[q], zv, aU);
    }
    wred2(aD, aU);
    if (lane == 0) { astore(dC + r, aD); astore(uC + r, aU); }
  }
  __syncthreads();
  sZ[tid] = z0[tid];
  float biasr = m_out_b[tid];
  incc(bar + CNT_A, bid, tid);

  // ---- main recurrence
  for (int t = 2; t <= 256; ++t) {
    // ---------- Phase A ----------
    if (t == 2) waitc(bar + CNT_A, 8, tid, lane);
    else        waitc(bar + CNT_DE, 4 * (t - 2), tid, lane);
    float s;
    if (t > 2) {
      s = sZ[tid] + biasr;
#pragma unroll
      for (int i = 0; i < 16; ++i) {
        float2 a = aload2(zpT + (size_t)tid * 32 + 2 * i);
        s += a.x + a.y;
      }
      sZ[tid] = s;
    } else {
      s = sZ[tid];
    }
    __syncthreads();
    if (t > 2 && (tid >> 4) == bid)
      astore(Z + (size_t)(t - 1) * 1024 + tid, s);
    {
      int r = 16 * bid + wave;
      float aD = 0.f, aU = 0.f;
#pragma unroll
      for (int q = 0; q < 16; ++q) {
        float zv = sZ[lane + 64 * q];
        aD = fmaf(rB[q], zv, aD);
        aU = fmaf(rW[q], zv, aU);
      }
      wred2(aD, aU);
      if (lane == 0) {
        astore(dC + (size_t)(t - 1) * 1024 + r, aD);
        astore(uC + (size_t)(t - 1) * 1024 + r, aU);
        shP[wave] = aD * sZ[r];
      }
    }
    if (wave < 4) {
      int i = 4 * bid + wave;
      if (i <= t - 2) {
        const float* dr = dCn + (size_t)i * 1024;
        float acc = 0.f;
#pragma unroll
        for (int q = 0; q < 16; ++q) acc = fmaf(dr[lane + 64 * q], sZ[lane + 64 * q], acc);
        acc = wred(acc);
        if (lane == 0) astore(lg + i, acc);
      }
    }
    __syncthreads();
    if (tid == 0) {
      float p = 0.f;
#pragma unroll
      for (int w = 0; w < 16; ++w) p += shP[w];
      astore(lgp + bid, p);
    }
    incc(bar + CNT_A, bid, tid);

    // ---------- Phase SM ----------
    waitc(bar + CNT_A, 8 * t, tid, lane);
    {
      float lv = 0.f;
      if (tid <= t - 2) lv = aload(lg + tid);
      if (wave == 4) {
        float p = aload(lgp + lane);
        p = wred(p);
        if (lane == 0) shm0_ = p;
      }
      __syncthreads();
      float l = -1e30f;
      if (tid <= t - 2) l = lv * 0.03125f;
      if (tid == t - 1) l = shm0_ * 0.03125f;
      float mx = l;
#pragma unroll
      for (int o = 1; o < 64; o <<= 1) mx = fmaxf(mx, __shfl_xor(mx, o, 64));
      if (lane == 0) shM[wave] = mx;
      __syncthreads();
      float m = fmaxf(fmaxf(fmaxf(shM[0], shM[1]), fmaxf(shM[2], shM[3])), 0.f);
      float e = (tid <= t - 1) ? expf(l - m) : 0.f;
      float es = wred(e);
      if (lane == 0) shS[wave] = es;
      __syncthreads();
      float den = shS[0] + shS[1] + shS[2] + shS[3] + (float)(257 - t) * expf(-m);
      if (tid < 256) sA[tid] = e / den;
      __syncthreads();
      int c = tid & 15, ic = tid >> 4;
      int col = 16 * bid + c;
      float acc = 0.f;
#pragma unroll
      for (int j = 0; j < 4; ++j) {
        int i = ic + 64 * j;
        if (i <= t - 1) acc = fmaf(sA[i], uCn[(size_t)i * 1024 + col], acc);
      }
      sP[ic][c] = acc;
      __syncthreads();
      if (tid < 256) {
        int q = tid >> 4;
        sQ[q][c] = sP[4 * q][c] + sP[4 * q + 1][c] + sP[4 * q + 2][c] + sP[4 * q + 3][c];
      }
      __syncthreads();
      if (tid < 16) {
        float v = 0.f;
#pragma unroll
        for (int q = 0; q < 16; ++q) v += sQ[q][tid];
        v += m_in_b[16 * bid + tid];
        astore(f1 + 16 * bid + tid, lrelu(v));
      }
    }
    incc(bar + CNT_SM, bid, tid);

    // ---------- Phase C ----------
    waitc(bar + CNT_SM, 8 * (t - 1), tid, lane);
    sX[tid] = aload(f1 + tid);
    __syncthreads();
    {
      int r = 16 * bid + wave;
      const float* w = m_h0_w + (size_t)r * 1024;
      float acc = 0.f;
#pragma unroll
      for (int q = 0; q < 16; ++q) acc = fmaf(w[lane + 64 * q], sX[lane + 64 * q], acc);
      acc = wred(acc);
      if (lane == 0) astore(f2 + r, lrelu(acc + m_h0_b[r]));
    }
    incc(bar + CNT_C, bid, tid);

    // ---------- Phase DE (32 workers) ----------
    if (bid < 32) {
      waitc(bar + CNT_C, 8 * (t - 1), tid, lane);
      sX[tid] = aload(f2 + tid);
      __syncthreads();
#pragma unroll
      for (int u = 0; u < 2; ++u) {
        int cc = 2 * wave + u;
        int r = 32 * bid + cc;
        const float* w = m_h1_w + (size_t)r * 1024;
        float acc = 0.f;
#pragma unroll
        for (int q = 0; q < 16; ++q) acc = fmaf(w[lane + 64 * q], sX[lane + 64 * q], acc);
        acc = wred(acc);
        if (lane == 0) sF3[cc] = lrelu(acc + m_h1_b[r]);
      }
      __syncthreads();
      {
        const float* w = m_out_w + (size_t)tid * 1024 + 32 * bid;
        float acc = 0.f;
#pragma unroll
        for (int j = 0; j < 32; j += 4) {
          float4 wf = *(const float4*)(w + j);
          acc = fmaf(wf.x, sF3[j], acc);     acc = fmaf(wf.y, sF3[j + 1], acc);
          acc = fmaf(wf.z, sF3[j + 2], acc); acc = fmaf(wf.w, sF3[j + 3], acc);
        }
        astore(zpT + (size_t)tid * 32 + bid, acc);
      }
      incc(bar + CNT_DE, bid, tid);
    }
  }

  // ---- epilogue: z_256 -> Z[256]
  waitc(bar + CNT_DE, 4 * 255, tid, lane);
  {
    float s = sZ[tid] + biasr;
#pragma unroll
    for (int i = 0; i < 16; ++i) {
      float2 a = aload2(zpT + (size_t)tid * 32 + 2 * i);
      s += a.x + a.y;
    }
    if ((tid >> 4) == bid)
      astore(Z + (size_t)256 * 1024 + tid, s);
  }
}

extern "C" void kernel_launch(void* const* d_in, const int* in_sizes, int n_in,
                              void* d_out, int out_size, void* d_ws, size_t ws_size,
                              hipStream_t stream) {
  (void)in_sizes; (void)n_in; (void)out_size; (void)ws_size;
  hipMemsetAsync(d_ws, 0, 4096, stream);  // done-counters
  tcell<<<dim3(NBLK), dim3(NTHR), 0, stream>>>(
      (const float*)d_in[0],  (const float*)d_in[1],
      (const float*)d_in[2],  (const float*)d_in[3],  (const float*)d_in[4],
      (const float*)d_in[5],  (const float*)d_in[6],
      (const float*)d_in[7],  (const float*)d_in[8],
      (const float*)d_in[9],  (const float*)d_in[10],
      (const float*)d_in[11], (const float*)d_in[12],
      (const float*)d_in[13], (const float*)d_in[14],
      (const float*)d_in[15], (const float*)d_in[16],
      (const float*)d_in[17], (const float*)d_in[18],
      (const float*)d_in[19], (const float*)d_in[20],
      (float*)d_out, (float*)d_ws);
}

// Round 6
// 6123.270 us; speedup vs baseline: 1.7638x; 1.5267x over previous
//
#include <hip/hip_runtime.h>
#include <math.h>

// TransformerCell recurrence, 5 lean phases/step, 256 blocks x 256 threads.
// R5 + fix: full-row LDS staging (float4/thread; R5 loaded only 256/1024 elems).
//   A : read Z[t-1] (4KB, coalesced); append d_{t-1}=B z, U_{t-1}=W~ z
//       (B=W1@W2, W~=m_in_w@W3 rows in regs, 1 row/wave); logit lg[bid] =
//       dC[bid].z (cached row); partial of new-row logit -> lgp[bid].
//   SM: softmax over logits (+(257-t) zero rows), f1[4 cols] from cached uC slice.
//   C : f2[4 rows] = lrelu(m_h0_w f1 + b)
//   D : f3[4 rows] = lrelu(m_h1_w f2 + b)
//   E : z[4 elems] += m_out_w f3 + b -> Z[t] slice (zprev in regs)
// Sync: ONE monotonic 32-line counter chain; arrival = tid0 fetch_add
// (8 blocks/line); detect = 32-lane vector atomic poll, no release stage.
// Coherence: per-step vectors (lg/lgp/f1/f2/f3) relaxed agent atomics (LLC);
// append-once data (dC/uC/Z) atomic-written, normal-cached-read strictly after
// first write (first touch always follows the write).

#define NTHR 256
#define NBLK 256

#define OFF_DC  1024          /* dC[257][1024] */
#define OFF_UC  264192        /* uC[257][1024] */
#define OFF_LG  527360        /* 256 */
#define OFF_LGP 527616        /* 256 */
#define OFF_F1  527872
#define OFF_F2  528896
#define OFF_F3  529920

__device__ __forceinline__ float aload(const float* p) {
  return __hip_atomic_load((float*)p, __ATOMIC_RELAXED, __HIP_MEMORY_SCOPE_AGENT);
}
__device__ __forceinline__ void astore(float* p, float v) {
  __hip_atomic_store(p, v, __ATOMIC_RELAXED, __HIP_MEMORY_SCOPE_AGENT);
}
__device__ __forceinline__ float2 aload2(const float* p) {
  double d = __hip_atomic_load((double*)p, __ATOMIC_RELAXED, __HIP_MEMORY_SCOPE_AGENT);
  return __builtin_bit_cast(float2, d);
}
__device__ __forceinline__ int aloadI(const int* p) {
  return __hip_atomic_load((int*)p, __ATOMIC_RELAXED, __HIP_MEMORY_SCOPE_AGENT);
}
__device__ __forceinline__ int afaddI(int* p) {
  return __hip_atomic_fetch_add(p, 1, __ATOMIC_RELAXED, __HIP_MEMORY_SCOPE_AGENT);
}

__device__ __forceinline__ float wred(float v) {
#pragma unroll
  for (int o = 1; o < 64; o <<= 1) v += __shfl_xor(v, o, 64);
  return v;
}
__device__ __forceinline__ void wred2(float& a, float& b) {
#pragma unroll
  for (int o = 1; o < 64; o <<= 1) { a += __shfl_xor(a, o, 64); b += __shfl_xor(b, o, 64); }
}
__device__ __forceinline__ float wmax(float v) {
#pragma unroll
  for (int o = 1; o < 64; o <<= 1) v = fmaxf(v, __shfl_xor(v, o, 64));
  return v;
}
__device__ __forceinline__ float lrelu(float x) { return x > 0.f ? x : 0.01f * x; }

// single monotonic sync chain: 32 lines, 8 blocks/line, direct poll
__device__ __forceinline__ void gsync(int* bar, int g, int bid, int tid, int lane) {
  asm volatile("" ::: "memory");
  __builtin_amdgcn_s_waitcnt(0);
  __syncthreads();
  if (tid == 0) afaddI(bar + (bid & 31) * 16);
  if (tid < 64) {
    const int tgt = 8 * g;
    for (;;) {
      int v = (lane < 32) ? aloadI(bar + lane * 16) : 0x7fffffff;
      if (__all(v >= tgt)) break;
      __builtin_amdgcn_s_sleep(2);
    }
  }
  __syncthreads();
  asm volatile("" ::: "memory");
}

__device__ __forceinline__ void stage(float* sX, const float* src, int tid) {
  float2 a = aload2(src + 2 * tid);
  float2 b = aload2(src + 2 * tid + 512);
  *(float2*)(sX + 2 * tid) = a;
  *(float2*)(sX + 2 * tid + 512) = b;
  __syncthreads();
}

__global__ void __launch_bounds__(NTHR) tcell(
    const float* __restrict__ mu, const float* __restrict__ z0,
    const float* __restrict__ W1, const float* __restrict__ W2, const float* __restrict__ W3,
    const float* __restrict__ p_in_w, const float* __restrict__ p_in_b,
    const float* __restrict__ p_h0_w, const float* __restrict__ p_h0_b,
    const float* __restrict__ p_h1_w, const float* __restrict__ p_h1_b,
    const float* __restrict__ p_out_w, const float* __restrict__ p_out_b,
    const float* __restrict__ m_in_w, const float* __restrict__ m_in_b,
    const float* __restrict__ m_h0_w, const float* __restrict__ m_h0_b,
    const float* __restrict__ m_h1_w, const float* __restrict__ m_h1_b,
    const float* __restrict__ m_out_w, const float* __restrict__ m_out_b,
    float* __restrict__ Z, float* __restrict__ ws) {
  const int tid = threadIdx.x;
  const int bid = blockIdx.x;
  const int lane = tid & 63;
  const int wave = tid >> 6;
  const int r = 4 * bid + wave;          // this wave's global row/elem id

  int* bar = (int*)ws;
  float* dC = ws + OFF_DC;
  float* uC = ws + OFF_UC;
  float* lg = ws + OFF_LG;
  float* lgp = ws + OFF_LGP;
  float* f1 = ws + OFF_F1;
  float* f2 = ws + OFF_F2;
  float* f3 = ws + OFF_F3;
  const float* dCn = dC;
  const float* uCn = uC;

  __shared__ float sZ[1024];
  __shared__ float sX[1024];
  __shared__ float sR[256];
  __shared__ float shW[8];
  __shared__ float shS;

  int g = 0;

  // ---- P0: rB4/rW4 = own row of B=W1@W2, W~=m_in_w@W3 (1 row/wave); p_in
  float4 rB4[4], rW4[4];
#pragma unroll
  for (int q = 0; q < 4; ++q) {
    rB4[q] = make_float4(0.f, 0.f, 0.f, 0.f);
    rW4[q] = make_float4(0.f, 0.f, 0.f, 0.f);
  }
  {
    const float* __restrict__ w1r = W1 + (size_t)r * 512;
    const float* __restrict__ mir = m_in_w + (size_t)r * 512;
    for (int k = 0; k < 512; k += 2) {
      float w1a = w1r[k], w1b = w1r[k + 1];
      float mia = mir[k], mib = mir[k + 1];
      const float* w2a = W2 + (size_t)k * 1024 + 4 * lane;
      const float* w3a = W3 + (size_t)k * 1024 + 4 * lane;
#pragma unroll
      for (int q = 0; q < 4; ++q) {
        float4 a0 = *(const float4*)(w2a + 256 * q);
        float4 a1 = *(const float4*)(w2a + 1024 + 256 * q);
        float4 b0 = *(const float4*)(w3a + 256 * q);
        float4 b1 = *(const float4*)(w3a + 1024 + 256 * q);
        rB4[q].x = fmaf(w1a, a0.x, fmaf(w1b, a1.x, rB4[q].x));
        rB4[q].y = fmaf(w1a, a0.y, fmaf(w1b, a1.y, rB4[q].y));
        rB4[q].z = fmaf(w1a, a0.z, fmaf(w1b, a1.z, rB4[q].z));
        rB4[q].w = fmaf(w1a, a0.w, fmaf(w1b, a1.w, rB4[q].w));
        rW4[q].x = fmaf(mia, b0.x, fmaf(mib, b1.x, rW4[q].x));
        rW4[q].y = fmaf(mia, b0.y, fmaf(mib, b1.y, rW4[q].y));
        rW4[q].z = fmaf(mia, b0.z, fmaf(mib, b1.z, rW4[q].z));
        rW4[q].w = fmaf(mia, b0.w, fmaf(mib, b1.w, rW4[q].w));
      }
    }
    float acc = p_in_w[(size_t)r * 64 + lane] * mu[lane];
    acc = wred(acc);
    if (lane == 0) astore(f1 + r, lrelu(acc + p_in_b[r]));
  }
  gsync(bar, ++g, bid, tid, lane);

  // ---- P1: f2 = lrelu(p_h0_w f1 + b)
  stage(sX, f1, tid);
  {
    const float* w = p_h0_w + (size_t)r * 1024 + 4 * lane;
    float acc = 0.f;
#pragma unroll
    for (int q = 0; q < 4; ++q) {
      float4 wf = *(const float4*)(w + 256 * q);
      float4 xf = *(const float4*)(sX + 4 * lane + 256 * q);
      acc = fmaf(wf.x, xf.x, acc); acc = fmaf(wf.y, xf.y, acc);
      acc = fmaf(wf.z, xf.z, acc); acc = fmaf(wf.w, xf.w, acc);
    }
    acc = wred(acc);
    if (lane == 0) astore(f2 + r, lrelu(acc + p_h0_b[r]));
  }
  gsync(bar, ++g, bid, tid, lane);

  // ---- P2: f3 = lrelu(p_h1_w f2 + b)
  stage(sX, f2, tid);
  {
    const float* w = p_h1_w + (size_t)r * 1024 + 4 * lane;
    float acc = 0.f;
#pragma unroll
    for (int q = 0; q < 4; ++q) {
      float4 wf = *(const float4*)(w + 256 * q);
      float4 xf = *(const float4*)(sX + 4 * lane + 256 * q);
      acc = fmaf(wf.x, xf.x, acc); acc = fmaf(wf.y, xf.y, acc);
      acc = fmaf(wf.z, xf.z, acc); acc = fmaf(wf.w, xf.w, acc);
    }
    acc = wred(acc);
    if (lane == 0) astore(f3 + r, lrelu(acc + p_h1_b[r]));
  }
  gsync(bar, ++g, bid, tid, lane);

  // ---- P3: Z[0] = p_out_w f3 + b;  Z[1] = z0
  stage(sX, f3, tid);
  {
    const float* w = p_out_w + (size_t)r * 1024 + 4 * lane;
    float acc = 0.f;
#pragma unroll
    for (int q = 0; q < 4; ++q) {
      float4 wf = *(const float4*)(w + 256 * q);
      float4 xf = *(const float4*)(sX + 4 * lane + 256 * q);
      acc = fmaf(wf.x, xf.x, acc); acc = fmaf(wf.y, xf.y, acc);
      acc = fmaf(wf.z, xf.z, acc); acc = fmaf(wf.w, xf.w, acc);
    }
    acc = wred(acc);
    if (lane == 0) astore(Z + r, acc + p_out_b[r]);
  }
  if (bid < 4) astore(Z + 1024 + bid * 256 + tid, z0[bid * 256 + tid]);
  gsync(bar, ++g, bid, tid, lane);

  // ---- P4: append row 0 (d_0, U_0 from Z[0]; FULL-ROW stage, float4/thread)
  {
    *(float4*)(sZ + 4 * tid) = *(const float4*)(Z + 4 * tid);
    __syncthreads();
    float aD = 0.f, aU = 0.f;
#pragma unroll
    for (int q = 0; q < 4; ++q) {
      float4 zf = *(const float4*)(sZ + 4 * lane + 256 * q);
      aD = fmaf(rB4[q].x, zf.x, aD); aD = fmaf(rB4[q].y, zf.y, aD);
      aD = fmaf(rB4[q].z, zf.z, aD); aD = fmaf(rB4[q].w, zf.w, aD);
      aU = fmaf(rW4[q].x, zf.x, aU); aU = fmaf(rW4[q].y, zf.y, aU);
      aU = fmaf(rW4[q].z, zf.z, aU); aU = fmaf(rW4[q].w, zf.w, aU);
    }
    wred2(aD, aU);
    if (lane == 0) { astore(dC + r, aD); astore(uC + r, aU); }
    __syncthreads();
  }
  float zprev_e = z0[r];                 // z_1 slice element (uniform per wave)
  float mob = m_out_b[r];
  gsync(bar, ++g, bid, tid, lane);

  // ---- main recurrence
  for (int t = 2; t <= 256; ++t) {
    // ---------- Phase A ----------
    {
      *(float4*)(sZ + 4 * tid) =
          *(const float4*)(Z + (size_t)(t - 1) * 1024 + 4 * tid);  // full row
      __syncthreads();
      float aD = 0.f, aU = 0.f;
#pragma unroll
      for (int q = 0; q < 4; ++q) {
        float4 zf = *(const float4*)(sZ + 4 * lane + 256 * q);
        aD = fmaf(rB4[q].x, zf.x, aD); aD = fmaf(rB4[q].y, zf.y, aD);
        aD = fmaf(rB4[q].z, zf.z, aD); aD = fmaf(rB4[q].w, zf.w, aD);
        aU = fmaf(rW4[q].x, zf.x, aU); aU = fmaf(rW4[q].y, zf.y, aU);
        aU = fmaf(rW4[q].z, zf.z, aU); aU = fmaf(rW4[q].w, zf.w, aU);
      }
      wred2(aD, aU);
      if (lane == 0) {
        astore(dC + (size_t)(t - 1) * 1024 + r, aD);
        astore(uC + (size_t)(t - 1) * 1024 + r, aU);
        shW[wave] = aD * sZ[r];
      }
      // logit for row i = bid (cached dC row)
      float part = 0.f;
      if (bid <= t - 2) {
        const float* dr = dCn + (size_t)bid * 1024;
#pragma unroll
        for (int j = 0; j < 4; ++j)
          part = fmaf(dr[tid + 256 * j], sZ[tid + 256 * j], part);
      }
      sR[tid] = part;
      __syncthreads();
      if (tid < 128) sR[tid] += sR[tid + 128];
      __syncthreads();
      if (tid < 64) {
        float v = sR[tid] + sR[tid + 64];
        v = wred(v);
        if (tid == 0) {
          if (bid <= t - 2) astore(lg + bid, v);
          astore(lgp + bid, shW[0] + shW[1] + shW[2] + shW[3]);
        }
      }
    }
    gsync(bar, ++g, bid, tid, lane);

    // ---------- Phase SM ----------
    {
      float lgv = (tid <= t - 2) ? aload(lg + tid) : 0.f;
      if (wave == 0) {
        float2 pa = aload2(lgp + 4 * lane);
        float2 pb = aload2(lgp + 4 * lane + 2);
        float s = pa.x + pa.y + pb.x + pb.y;
        s = wred(s);
        if (lane == 0) shS = s;
      }
      __syncthreads();
      float l = -1e30f;
      if (tid <= t - 2) l = lgv * 0.03125f;
      if (tid == t - 1) l = shS * 0.03125f;
      float mx = wmax(l);
      if (lane == 0) shW[wave] = mx;
      __syncthreads();
      float m = fmaxf(fmaxf(fmaxf(shW[0], shW[1]), fmaxf(shW[2], shW[3])), 0.f);
      float e = (tid <= t - 1) ? __expf(l - m) : 0.f;
      float es = wred(e);
      if (lane == 0) shW[4 + wave] = es;
      __syncthreads();
      float den = shW[4] + shW[5] + shW[6] + shW[7] + (float)(257 - t) * __expf(-m);
      sR[tid] = e / den;                 // a_i
      __syncthreads();
      // f1 cols [4*bid .. 4*bid+3]: tid = 4*ic + c
      int c = tid & 3, ic = tid >> 2;
      int col = 4 * bid + c;
      float acc = 0.f;
#pragma unroll
      for (int j = 0; j < 4; ++j) {
        int i = ic + 64 * j;
        if (i <= t - 1) acc = fmaf(sR[i], uCn[(size_t)i * 1024 + col], acc);
      }
      sX[tid] = acc;
      __syncthreads();
      if (tid < 128) sX[tid] += sX[tid + 128];
      __syncthreads();
      if (tid < 64) sX[tid] += sX[tid + 64];
      __syncthreads();
      if (tid < 32) sX[tid] += sX[tid + 32];
      __syncthreads();
      if (tid < 16) sX[tid] += sX[tid + 16];
      __syncthreads();
      if (tid < 8) sX[tid] += sX[tid + 8];
      __syncthreads();
      if (tid < 4) {
        float v = sX[tid] + sX[tid + 4];
        v += m_in_b[4 * bid + tid];
        astore(f1 + 4 * bid + tid, lrelu(v));
      }
    }
    gsync(bar, ++g, bid, tid, lane);

    // ---------- Phase C: f2 ----------
    stage(sX, f1, tid);
    {
      const float* w = m_h0_w + (size_t)r * 1024 + 4 * lane;
      float acc = 0.f;
#pragma unroll
      for (int q = 0; q < 4; ++q) {
        float4 wf = *(const float4*)(w + 256 * q);
        float4 xf = *(const float4*)(sX + 4 * lane + 256 * q);
        acc = fmaf(wf.x, xf.x, acc); acc = fmaf(wf.y, xf.y, acc);
        acc = fmaf(wf.z, xf.z, acc); acc = fmaf(wf.w, xf.w, acc);
      }
      acc = wred(acc);
      if (lane == 0) astore(f2 + r, lrelu(acc + m_h0_b[r]));
    }
    gsync(bar, ++g, bid, tid, lane);

    // ---------- Phase D: f3 ----------
    stage(sX, f2, tid);
    {
      const float* w = m_h1_w + (size_t)r * 1024 + 4 * lane;
      float acc = 0.f;
#pragma unroll
      for (int q = 0; q < 4; ++q) {
        float4 wf = *(const float4*)(w + 256 * q);
        float4 xf = *(const float4*)(sX + 4 * lane + 256 * q);
        acc = fmaf(wf.x, xf.x, acc); acc = fmaf(wf.y, xf.y, acc);
        acc = fmaf(wf.z, xf.z, acc); acc = fmaf(wf.w, xf.w, acc);
      }
      acc = wred(acc);
      if (lane == 0) astore(f3 + r, lrelu(acc + m_h1_b[r]));
    }
    gsync(bar, ++g, bid, tid, lane);

    // ---------- Phase E: z slice ----------
    stage(sX, f3, tid);
    {
      const float* w = m_out_w + (size_t)r * 1024 + 4 * lane;
      float acc = 0.f;
#pragma unroll
      for (int q = 0; q < 4; ++q) {
        float4 wf = *(const float4*)(w + 256 * q);
        float4 xf = *(const float4*)(sX + 4 * lane + 256 * q);
        acc = fmaf(wf.x, xf.x, acc); acc = fmaf(wf.y, xf.y, acc);
        acc = fmaf(wf.z, xf.z, acc); acc = fmaf(wf.w, xf.w, acc);
      }
      acc = wred(acc);
      float znew = zprev_e + acc + mob;
      zprev_e = znew;
      if (lane == 0) astore(Z + (size_t)t * 1024 + r, znew);
    }
    gsync(bar, ++g, bid, tid, lane);
  }
}

extern "C" void kernel_launch(void* const* d_in, const int* in_sizes, int n_in,
                              void* d_out, int out_size, void* d_ws, size_t ws_size,
                              hipStream_t stream) {
  (void)in_sizes; (void)n_in; (void)out_size; (void)ws_size;
  hipMemsetAsync(d_ws, 0, 4096, stream);  // sync-chain counters
  tcell<<<dim3(NBLK), dim3(NTHR), 0, stream>>>(
      (const float*)d_in[0],  (const float*)d_in[1],
      (const float*)d_in[2],  (const float*)d_in[3],  (const float*)d_in[4],
      (const float*)d_in[5],  (const float*)d_in[6],
      (const float*)d_in[7],  (const float*)d_in[8],
      (const float*)d_in[9],  (const float*)d_in[10],
      (const float*)d_in[11], (const float*)d_in[12],
      (const float*)d_in[13], (const float*)d_in[14],
      (const float*)d_in[15], (const float*)d_in[16],
      (const float*)d_in[17], (const float*)d_in[18],
      (const float*)d_in[19], (const float*)d_in[20],
      (float*)d_out, (float*)d_ws);
}

// Round 7
// 5434.565 us; speedup vs baseline: 1.9873x; 1.1267x over previous
//
#include <hip/hip_runtime.h>
#include <math.h>

// TransformerCell recurrence, 5 lean phases/step, 256 blocks x 256 threads.
// R6 + de-contention: broadcast buffers (f1/f2/f3/lg/lgp) replicated x8 so each
// LLC line has <=32 atomic readers; uC moved to LDS (block-diagonal comm:
// block b only reads the uC cols it wrote); dC pre-scaled by 1/32; SM phase
// restructured to wave-per-column (3 syncthreads).
//   A : stage Z[t-1] (normal, L2-absorbed); append d(scaled)/U (1 row/wave,
//       B=W1@W2, W~=m_in_w@W3 in regs); U -> LDS sU; logit lg[bid]=d_bid.z
//       (L1-resident dC row, single-reader); new-row partial -> lgp[bid]. x8 reps.
//   SM: softmax (+(257-t) zero rows); f1 col/wave from LDS sU. x8 reps.
//   C : f2[4 rows] = lrelu(m_h0_w f1 + b). x8 reps.
//   D : f3[4 rows] = lrelu(m_h1_w f2 + b). x8 reps.
//   E : z[4 elems] += m_out_w f3 + b -> Z[t] (single copy; zprev in regs).
// Sync: 8-line monotonic counter chain; arrival = tid0 fetch_add (line bid&7,
// 32 blocks/line); detect = 8-lane vector atomic poll (v >= 32*g).
// Coherence: per-step buffers via relaxed agent atomics (LLC); append-once
// (dC/Z) atomic-written, normal-read strictly after write; replay-stale L1/L2
// lines hold identical values (deterministic), so caching is safe.

#define NTHR 256
#define NBLK 256

#define OFF_DC  1024            /* dC[257][1024] */
#define OFF_LGR 264192          /* lgrep[8][256] */
#define OFF_LGP 266240          /* lgprep[8][256] */
#define OFF_F1R 268288          /* f1rep[8][1024] */
#define OFF_F2R 276480          /* f2rep[8][1024] */
#define OFF_F3R 284672          /* f3rep[8][1024] */

__device__ __forceinline__ float aload(const float* p) {
  return __hip_atomic_load((float*)p, __ATOMIC_RELAXED, __HIP_MEMORY_SCOPE_AGENT);
}
__device__ __forceinline__ void astore(float* p, float v) {
  __hip_atomic_store(p, v, __ATOMIC_RELAXED, __HIP_MEMORY_SCOPE_AGENT);
}
__device__ __forceinline__ float2 aload2(const float* p) {
  double d = __hip_atomic_load((double*)p, __ATOMIC_RELAXED, __HIP_MEMORY_SCOPE_AGENT);
  return __builtin_bit_cast(float2, d);
}
__device__ __forceinline__ int aloadI(const int* p) {
  return __hip_atomic_load((int*)p, __ATOMIC_RELAXED, __HIP_MEMORY_SCOPE_AGENT);
}
__device__ __forceinline__ int afaddI(int* p) {
  return __hip_atomic_fetch_add(p, 1, __ATOMIC_RELAXED, __HIP_MEMORY_SCOPE_AGENT);
}

__device__ __forceinline__ float wred(float v) {
#pragma unroll
  for (int o = 1; o < 64; o <<= 1) v += __shfl_xor(v, o, 64);
  return v;
}
__device__ __forceinline__ void wred2(float& a, float& b) {
#pragma unroll
  for (int o = 1; o < 64; o <<= 1) { a += __shfl_xor(a, o, 64); b += __shfl_xor(b, o, 64); }
}
__device__ __forceinline__ float wmax(float v) {
#pragma unroll
  for (int o = 1; o < 64; o <<= 1) v = fmaxf(v, __shfl_xor(v, o, 64));
  return v;
}
__device__ __forceinline__ float lrelu(float x) { return x > 0.f ? x : 0.01f * x; }

// 8-line monotonic chain; 32 blocks arrive per line; detect when all >= 32*g
__device__ __forceinline__ void gsync(int* bar, int g, int bid, int tid, int lane) {
  asm volatile("" ::: "memory");
  __builtin_amdgcn_s_waitcnt(0);
  __syncthreads();
  if (tid == 0) afaddI(bar + (bid & 7) * 16);
  if (tid < 64) {
    const int tgt = 32 * g;
    for (;;) {
      int v = (lane < 8) ? aloadI(bar + lane * 16) : 0x7fffffff;
      if (__all(v >= tgt)) break;
      __builtin_amdgcn_s_sleep(2);
    }
  }
  __syncthreads();
  asm volatile("" ::: "memory");
}

// stage a 1024-vector replica into LDS (4 floats/thread)
__device__ __forceinline__ void stageR(float* sX, const float* rep, int tid) {
  float2 a = aload2(rep + 2 * tid);
  float2 b = aload2(rep + 2 * tid + 512);
  *(float2*)(sX + 2 * tid) = a;
  *(float2*)(sX + 2 * tid + 512) = b;
  __syncthreads();
}

__global__ void __launch_bounds__(NTHR) tcell(
    const float* __restrict__ mu, const float* __restrict__ z0,
    const float* __restrict__ W1, const float* __restrict__ W2, const float* __restrict__ W3,
    const float* __restrict__ p_in_w, const float* __restrict__ p_in_b,
    const float* __restrict__ p_h0_w, const float* __restrict__ p_h0_b,
    const float* __restrict__ p_h1_w, const float* __restrict__ p_h1_b,
    const float* __restrict__ p_out_w, const float* __restrict__ p_out_b,
    const float* __restrict__ m_in_w, const float* __restrict__ m_in_b,
    const float* __restrict__ m_h0_w, const float* __restrict__ m_h0_b,
    const float* __restrict__ m_h1_w, const float* __restrict__ m_h1_b,
    const float* __restrict__ m_out_w, const float* __restrict__ m_out_b,
    float* __restrict__ Z, float* __restrict__ ws) {
  const int tid = threadIdx.x;
  const int bid = blockIdx.x;
  const int lane = tid & 63;
  const int wave = tid >> 6;
  const int r = 4 * bid + wave;          // this wave's global row/elem id
  const int rep = (bid & 7);

  int* bar = (int*)ws;
  float* dC = ws + OFF_DC;
  float* lgr = ws + OFF_LGR;
  float* lgp = ws + OFF_LGP;
  float* f1r = ws + OFF_F1R;
  float* f2r = ws + OFF_F2R;
  float* f3r = ws + OFF_F3R;
  const float* dCn = dC;

  __shared__ float sZ[1024];
  __shared__ float sX[1024];
  __shared__ float sR[256];
  __shared__ float sU[4][257];
  __shared__ float shW[8];
  __shared__ float shS;

  int g = 0;

  // ---- P0: rB4/rW4 = own row of B=W1@W2, W~=m_in_w@W3 (1 row/wave); p_in
  float4 rB4[4], rW4[4];
#pragma unroll
  for (int q = 0; q < 4; ++q) {
    rB4[q] = make_float4(0.f, 0.f, 0.f, 0.f);
    rW4[q] = make_float4(0.f, 0.f, 0.f, 0.f);
  }
  {
    const float* __restrict__ w1r = W1 + (size_t)r * 512;
    const float* __restrict__ mir = m_in_w + (size_t)r * 512;
    for (int k = 0; k < 512; k += 2) {
      float w1a = w1r[k], w1b = w1r[k + 1];
      float mia = mir[k], mib = mir[k + 1];
      const float* w2a = W2 + (size_t)k * 1024 + 4 * lane;
      const float* w3a = W3 + (size_t)k * 1024 + 4 * lane;
#pragma unroll
      for (int q = 0; q < 4; ++q) {
        float4 a0 = *(const float4*)(w2a + 256 * q);
        float4 a1 = *(const float4*)(w2a + 1024 + 256 * q);
        float4 b0 = *(const float4*)(w3a + 256 * q);
        float4 b1 = *(const float4*)(w3a + 1024 + 256 * q);
        rB4[q].x = fmaf(w1a, a0.x, fmaf(w1b, a1.x, rB4[q].x));
        rB4[q].y = fmaf(w1a, a0.y, fmaf(w1b, a1.y, rB4[q].y));
        rB4[q].z = fmaf(w1a, a0.z, fmaf(w1b, a1.z, rB4[q].z));
        rB4[q].w = fmaf(w1a, a0.w, fmaf(w1b, a1.w, rB4[q].w));
        rW4[q].x = fmaf(mia, b0.x, fmaf(mib, b1.x, rW4[q].x));
        rW4[q].y = fmaf(mia, b0.y, fmaf(mib, b1.y, rW4[q].y));
        rW4[q].z = fmaf(mia, b0.z, fmaf(mib, b1.z, rW4[q].z));
        rW4[q].w = fmaf(mia, b0.w, fmaf(mib, b1.w, rW4[q].w));
      }
    }
    float acc = p_in_w[(size_t)r * 64 + lane] * mu[lane];
    acc = wred(acc);
    if (lane == 0) {
      float v = lrelu(acc + p_in_b[r]);
#pragma unroll
      for (int j = 0; j < 8; ++j) astore(f1r + j * 1024 + r, v);
    }
  }
  gsync(bar, ++g, bid, tid, lane);

  // ---- P1: f2 = lrelu(p_h0_w f1 + b)
  stageR(sX, f1r + rep * 1024, tid);
  {
    const float* w = p_h0_w + (size_t)r * 1024 + 4 * lane;
    float acc = 0.f;
#pragma unroll
    for (int q = 0; q < 4; ++q) {
      float4 wf = *(const float4*)(w + 256 * q);
      float4 xf = *(const float4*)(sX + 4 * lane + 256 * q);
      acc = fmaf(wf.x, xf.x, acc); acc = fmaf(wf.y, xf.y, acc);
      acc = fmaf(wf.z, xf.z, acc); acc = fmaf(wf.w, xf.w, acc);
    }
    acc = wred(acc);
    if (lane == 0) {
      float v = lrelu(acc + p_h0_b[r]);
#pragma unroll
      for (int j = 0; j < 8; ++j) astore(f2r + j * 1024 + r, v);
    }
  }
  gsync(bar, ++g, bid, tid, lane);

  // ---- P2: f3 = lrelu(p_h1_w f2 + b)
  stageR(sX, f2r + rep * 1024, tid);
  {
    const float* w = p_h1_w + (size_t)r * 1024 + 4 * lane;
    float acc = 0.f;
#pragma unroll
    for (int q = 0; q < 4; ++q) {
      float4 wf = *(const float4*)(w + 256 * q);
      float4 xf = *(const float4*)(sX + 4 * lane + 256 * q);
      acc = fmaf(wf.x, xf.x, acc); acc = fmaf(wf.y, xf.y, acc);
      acc = fmaf(wf.z, xf.z, acc); acc = fmaf(wf.w, xf.w, acc);
    }
    acc = wred(acc);
    if (lane == 0) {
      float v = lrelu(acc + p_h1_b[r]);
#pragma unroll
      for (int j = 0; j < 8; ++j) astore(f3r + j * 1024 + r, v);
    }
  }
  gsync(bar, ++g, bid, tid, lane);

  // ---- P3: Z[0] = p_out_w f3 + b;  Z[1] = z0
  stageR(sX, f3r + rep * 1024, tid);
  {
    const float* w = p_out_w + (size_t)r * 1024 + 4 * lane;
    float acc = 0.f;
#pragma unroll
    for (int q = 0; q < 4; ++q) {
      float4 wf = *(const float4*)(w + 256 * q);
      float4 xf = *(const float4*)(sX + 4 * lane + 256 * q);
      acc = fmaf(wf.x, xf.x, acc); acc = fmaf(wf.y, xf.y, acc);
      acc = fmaf(wf.z, xf.z, acc); acc = fmaf(wf.w, xf.w, acc);
    }
    acc = wred(acc);
    if (lane == 0) astore(Z + r, acc + p_out_b[r]);
  }
  if (bid < 4) astore(Z + 1024 + bid * 256 + tid, z0[bid * 256 + tid]);
  gsync(bar, ++g, bid, tid, lane);

  // ---- P4: append row 0 (d_0 scaled, U_0 -> LDS) from Z[0]
  {
    *(float4*)(sZ + 4 * tid) = *(const float4*)(Z + 4 * tid);
    __syncthreads();
    float aD = 0.f, aU = 0.f;
#pragma unroll
    for (int q = 0; q < 4; ++q) {
      float4 zf = *(const float4*)(sZ + 4 * lane + 256 * q);
      aD = fmaf(rB4[q].x, zf.x, aD); aD = fmaf(rB4[q].y, zf.y, aD);
      aD = fmaf(rB4[q].z, zf.z, aD); aD = fmaf(rB4[q].w, zf.w, aD);
      aU = fmaf(rW4[q].x, zf.x, aU); aU = fmaf(rW4[q].y, zf.y, aU);
      aU = fmaf(rW4[q].z, zf.z, aU); aU = fmaf(rW4[q].w, zf.w, aU);
    }
    wred2(aD, aU);
    if (lane == 0) {
      astore(dC + r, aD * 0.03125f);
      sU[wave][0] = aU;
    }
    __syncthreads();
  }
  float zprev_e = z0[r];                 // z_1 slice element
  float mob = m_out_b[r];
  gsync(bar, ++g, bid, tid, lane);

  // ---- main recurrence
  for (int t = 2; t <= 256; ++t) {
    // ---------- Phase A ----------
    {
      *(float4*)(sZ + 4 * tid) =
          *(const float4*)(Z + (size_t)(t - 1) * 1024 + 4 * tid);  // normal, L2-absorbed
      __syncthreads();
      float aD = 0.f, aU = 0.f;
#pragma unroll
      for (int q = 0; q < 4; ++q) {
        float4 zf = *(const float4*)(sZ + 4 * lane + 256 * q);
        aD = fmaf(rB4[q].x, zf.x, aD); aD = fmaf(rB4[q].y, zf.y, aD);
        aD = fmaf(rB4[q].z, zf.z, aD); aD = fmaf(rB4[q].w, zf.w, aD);
        aU = fmaf(rW4[q].x, zf.x, aU); aU = fmaf(rW4[q].y, zf.y, aU);
        aU = fmaf(rW4[q].z, zf.z, aU); aU = fmaf(rW4[q].w, zf.w, aU);
      }
      wred2(aD, aU);
      if (lane == 0) {
        float dsc = aD * 0.03125f;
        astore(dC + (size_t)(t - 1) * 1024 + r, dsc);
        sU[wave][t - 1] = aU;
        shW[wave] = dsc * sZ[r];         // scaled partial for new-row logit
      }
      // logit for row i = bid (L1-resident dC row, single reader)
      float part = 0.f;
      if (bid <= t - 2) {
        const float* dr = dCn + (size_t)bid * 1024;
#pragma unroll
        for (int j = 0; j < 4; ++j)
          part = fmaf(dr[tid + 256 * j], sZ[tid + 256 * j], part);
      }
      sR[tid] = part;
      __syncthreads();
      if (wave == 0) {
        float v = sR[lane] + sR[lane + 64] + sR[lane + 128] + sR[lane + 192];
        v = wred(v);
        if (lane == 0) {
          if (bid <= t - 2) {
#pragma unroll
            for (int j = 0; j < 8; ++j) astore(lgr + j * 256 + bid, v);
          }
          float pl = shW[0] + shW[1] + shW[2] + shW[3];
#pragma unroll
          for (int j = 0; j < 8; ++j) astore(lgp + j * 256 + bid, pl);
        }
      }
    }
    gsync(bar, ++g, bid, tid, lane);

    // ---------- Phase SM ----------
    {
      float l = (tid <= t - 2) ? aload(lgr + rep * 256 + tid) : -1e30f;  // pre-scaled
      if (wave == 0) {
        float2 pa = aload2(lgp + rep * 256 + 4 * lane);
        float2 pb = aload2(lgp + rep * 256 + 4 * lane + 2);
        float s = pa.x + pa.y + pb.x + pb.y;
        s = wred(s);
        if (lane == 0) shS = s;
      }
      __syncthreads();
      if (tid == t - 1) l = shS;
      float mx = wmax(l);
      if (lane == 0) shW[wave] = mx;
      __syncthreads();
      float m = fmaxf(fmaxf(fmaxf(shW[0], shW[1]), fmaxf(shW[2], shW[3])), 0.f);
      float e = (tid <= t - 1) ? __expf(l - m) : 0.f;
      float es = wred(e);
      if (lane == 0) shW[4 + wave] = es;
      __syncthreads();
      float den = shW[4] + shW[5] + shW[6] + shW[7] + (float)(257 - t) * __expf(-m);
      sR[tid] = e / den;                 // a_i
      __syncthreads();
      // f1 col per wave: col = r, from LDS sU (block-diagonal comm)
      float acc = 0.f;
#pragma unroll
      for (int j = 0; j < 4; ++j) {
        int i = lane + 64 * j;
        if (i <= t - 1) acc = fmaf(sR[i], sU[wave][i], acc);
      }
      acc = wred(acc);
      if (lane == 0) {
        float v = lrelu(acc + m_in_b[r]);
#pragma unroll
        for (int j = 0; j < 8; ++j) astore(f1r + j * 1024 + r, v);
      }
    }
    gsync(bar, ++g, bid, tid, lane);

    // ---------- Phase C: f2 ----------
    stageR(sX, f1r + rep * 1024, tid);
    {
      const float* w = m_h0_w + (size_t)r * 1024 + 4 * lane;
      float acc = 0.f;
#pragma unroll
      for (int q = 0; q < 4; ++q) {
        float4 wf = *(const float4*)(w + 256 * q);
        float4 xf = *(const float4*)(sX + 4 * lane + 256 * q);
        acc = fmaf(wf.x, xf.x, acc); acc = fmaf(wf.y, xf.y, acc);
        acc = fmaf(wf.z, xf.z, acc); acc = fmaf(wf.w, xf.w, acc);
      }
      acc = wred(acc);
      if (lane == 0) {
        float v = lrelu(acc + m_h0_b[r]);
#pragma unroll
        for (int j = 0; j < 8; ++j) astore(f2r + j * 1024 + r, v);
      }
    }
    gsync(bar, ++g, bid, tid, lane);

    // ---------- Phase D: f3 ----------
    stageR(sX, f2r + rep * 1024, tid);
    {
      const float* w = m_h1_w + (size_t)r * 1024 + 4 * lane;
      float acc = 0.f;
#pragma unroll
      for (int q = 0; q < 4; ++q) {
        float4 wf = *(const float4*)(w + 256 * q);
        float4 xf = *(const float4*)(sX + 4 * lane + 256 * q);
        acc = fmaf(wf.x, xf.x, acc); acc = fmaf(wf.y, xf.y, acc);
        acc = fmaf(wf.z, xf.z, acc); acc = fmaf(wf.w, xf.w, acc);
      }
      acc = wred(acc);
      if (lane == 0) {
        float v = lrelu(acc + m_h1_b[r]);
#pragma unroll
        for (int j = 0; j < 8; ++j) astore(f3r + j * 1024 + r, v);
      }
    }
    gsync(bar, ++g, bid, tid, lane);

    // ---------- Phase E: z slice ----------
    stageR(sX, f3r + rep * 1024, tid);
    {
      const float* w = m_out_w + (size_t)r * 1024 + 4 * lane;
      float acc = 0.f;
#pragma unroll
      for (int q = 0; q < 4; ++q) {
        float4 wf = *(const float4*)(w + 256 * q);
        float4 xf = *(const float4*)(sX + 4 * lane + 256 * q);
        acc = fmaf(wf.x, xf.x, acc); acc = fmaf(wf.y, xf.y, acc);
        acc = fmaf(wf.z, xf.z, acc); acc = fmaf(wf.w, xf.w, acc);
      }
      acc = wred(acc);
      float znew = zprev_e + acc + mob;
      zprev_e = znew;
      if (lane == 0) astore(Z + (size_t)t * 1024 + r, znew);
    }
    gsync(bar, ++g, bid, tid, lane);
  }
}

extern "C" void kernel_launch(void* const* d_in, const int* in_sizes, int n_in,
                              void* d_out, int out_size, void* d_ws, size_t ws_size,
                              hipStream_t stream) {
  (void)in_sizes; (void)n_in; (void)out_size; (void)ws_size;
  hipMemsetAsync(d_ws, 0, 4096, stream);  // sync-chain counters
  tcell<<<dim3(NBLK), dim3(NTHR), 0, stream>>>(
      (const float*)d_in[0],  (const float*)d_in[1],
      (const float*)d_in[2],  (const float*)d_in[3],  (const float*)d_in[4],
      (const float*)d_in[5],  (const float*)d_in[6],
      (const float*)d_in[7],  (const float*)d_in[8],
      (const float*)d_in[9],  (const float*)d_in[10],
      (const float*)d_in[11], (const float*)d_in[12],
      (const float*)d_in[13], (const float*)d_in[14],
      (const float*)d_in[15], (const float*)d_in[16],
      (const float*)d_in[17], (const float*)d_in[18],
      (const float*)d_in[19], (const float*)d_in[20],
      (float*)d_out, (float*)d_ws);
}

// Round 8
// 4169.914 us; speedup vs baseline: 2.5900x; 1.3033x over previous
//
#include <hip/hip_runtime.h>
#include <math.h>

// TransformerCell recurrence — flag-fused dataflow, no global barriers in the
// main loop. 256 blocks x 512 threads.
// Each phase output is 16B chunks {payload2, pad, tag} stored with ONE
// global_store_dwordx4 sc0 sc1 (LLC, single transaction). Consumers poll the
// chunk itself until tag==t: sync and data are the same LLC trip.
// Phases/step: A (append d/U row, logits; aC {lg,lgp,tag}) -> SM (softmax +
// f1 -> smC) -> C (f2 -> cCh) -> D (f3 -> dCh) -> E (z -> eCh + Z row).
// Overwrite safety: every block produces in every phase => transitive
// dataflow ordering. dC cache rows: astore'd once, waitcnt-drained before the
// evidencing aC store, normal-cached-read by their single reader afterwards.
// Tags reset each launch by memset (48KB) => replay-deterministic, no hangs.

#define NTHR 512
#define NBLK 256

typedef int i4 __attribute__((ext_vector_type(4)));

__device__ __forceinline__ float i2f(int x) { return __int_as_float(x); }
__device__ __forceinline__ int f2i(float x) { return __float_as_int(x); }

__device__ __forceinline__ void astore(float* p, float v) {
  __hip_atomic_store(p, v, __ATOMIC_RELAXED, __HIP_MEMORY_SCOPE_AGENT);
}
__device__ __forceinline__ int aloadI(const int* p) {
  return __hip_atomic_load((int*)p, __ATOMIC_RELAXED, __HIP_MEMORY_SCOPE_AGENT);
}
__device__ __forceinline__ int afaddI(int* p) {
  return __hip_atomic_fetch_add(p, 1, __ATOMIC_RELAXED, __HIP_MEMORY_SCOPE_AGENT);
}

// fused-chunk primitives: 16B, cache-bypass (LLC-coherent)
__device__ __forceinline__ i4 poll16(const i4* p, int tag) {
  i4 v;
  for (;;) {
    asm volatile("global_load_dwordx4 %0, %1, off sc0 sc1\n\ts_waitcnt vmcnt(0)"
                 : "=&v"(v) : "v"(p) : "memory");
    if (v.w == tag) return v;
    __builtin_amdgcn_s_sleep(1);
  }
}
__device__ __forceinline__ void store16(i4* p, i4 v) {
  asm volatile("global_store_dwordx4 %0, %1, off sc0 sc1" :: "v"(p), "v"(v) : "memory");
}

__device__ __forceinline__ float wred(float v) {
#pragma unroll
  for (int o = 1; o < 64; o <<= 1) v += __shfl_xor(v, o, 64);
  return v;
}
__device__ __forceinline__ void wred2(float& a, float& b) {
#pragma unroll
  for (int o = 1; o < 64; o <<= 1) { a += __shfl_xor(a, o, 64); b += __shfl_xor(b, o, 64); }
}
__device__ __forceinline__ float wmax(float v) {
#pragma unroll
  for (int o = 1; o < 64; o <<= 1) v = fmaxf(v, __shfl_xor(v, o, 64));
  return v;
}
__device__ __forceinline__ float lrelu(float x) { return x > 0.f ? x : 0.01f * x; }

// single prologue barrier (after P4): 8 lines, 32 blocks/line
__device__ __forceinline__ void gsync1(int* bar, int bid, int tid, int lane) {
  asm volatile("" ::: "memory");
  __builtin_amdgcn_s_waitcnt(0);
  __syncthreads();
  if (tid == 0) afaddI(bar + (bid & 7) * 16);
  if (tid < 64) {
    for (;;) {
      int v = (lane < 8) ? aloadI(bar + lane * 16) : 0x7fffffff;
      if (__all(v >= 32)) break;
      __builtin_amdgcn_s_sleep(2);
    }
  }
  __syncthreads();
  asm volatile("" ::: "memory");
}

__global__ void __launch_bounds__(NTHR) tcell(
    const float* __restrict__ mu, const float* __restrict__ z0,
    const float* __restrict__ W1, const float* __restrict__ W2, const float* __restrict__ W3,
    const float* __restrict__ p_in_w, const float* __restrict__ p_in_b,
    const float* __restrict__ p_h0_w, const float* __restrict__ p_h0_b,
    const float* __restrict__ p_h1_w, const float* __restrict__ p_h1_b,
    const float* __restrict__ p_out_w, const float* __restrict__ p_out_b,
    const float* __restrict__ m_in_w, const float* __restrict__ m_in_b,
    const float* __restrict__ m_h0_w, const float* __restrict__ m_h0_b,
    const float* __restrict__ m_h1_w, const float* __restrict__ m_h1_b,
    const float* __restrict__ m_out_w, const float* __restrict__ m_out_b,
    float* __restrict__ Z, float* __restrict__ ws) {
  const int tid = threadIdx.x;
  const int bid = blockIdx.x;
  const int lane = tid & 63;
  const int wave = tid >> 6;            // 0..7
  const int r = 4 * bid + (wave & 3);   // row id for compute waves

  char* wsb = (char*)ws;
  int* bar = (int*)wsb;                 // [0, 4096)
  i4* aC  = (i4*)(wsb + 4096);          // 256 chunks {lg, lgp, 0, tag}
  i4* smC = (i4*)(wsb + 8192);          // 512 chunks f1
  i4* cCh = (i4*)(wsb + 16384);         // 512 chunks f2
  i4* dCh = (i4*)(wsb + 24576);         // 512 chunks f3
  i4* eCh = (i4*)(wsb + 32768);         // 512 chunks z
  i4* zmC = (i4*)(wsb + 40960);         // 512 chunks z_minus (prologue)
  float* dCc = (float*)(wsb + 49152);   // dC cache [257][1024], pre-scaled 1/32

  __shared__ float sZ[1024], sX[1024];
  __shared__ float sR[256], sLg[256], sLp[256];
  __shared__ float sU[4][257];
  __shared__ float shW[4], shQ[4], shS[4], shF[4];

  // ---- P0: waves 0-3 build B=W1@W2, W~=m_in_w@W3 rows (regs); wave 4: p_in
  float4 rB4[4], rW4[4];
  if (wave < 4) {
#pragma unroll
    for (int q = 0; q < 4; ++q) {
      rB4[q] = make_float4(0.f, 0.f, 0.f, 0.f);
      rW4[q] = make_float4(0.f, 0.f, 0.f, 0.f);
    }
    const float* __restrict__ w1r = W1 + (size_t)r * 512;
    const float* __restrict__ mir = m_in_w + (size_t)r * 512;
    for (int k = 0; k < 512; k += 2) {
      float w1a = w1r[k], w1b = w1r[k + 1];
      float mia = mir[k], mib = mir[k + 1];
      const float* w2a = W2 + (size_t)k * 1024 + 4 * lane;
      const float* w3a = W3 + (size_t)k * 1024 + 4 * lane;
#pragma unroll
      for (int q = 0; q < 4; ++q) {
        float4 a0 = *(const float4*)(w2a + 256 * q);
        float4 a1 = *(const float4*)(w2a + 1024 + 256 * q);
        float4 b0 = *(const float4*)(w3a + 256 * q);
        float4 b1 = *(const float4*)(w3a + 1024 + 256 * q);
        rB4[q].x = fmaf(w1a, a0.x, fmaf(w1b, a1.x, rB4[q].x));
        rB4[q].y = fmaf(w1a, a0.y, fmaf(w1b, a1.y, rB4[q].y));
        rB4[q].z = fmaf(w1a, a0.z, fmaf(w1b, a1.z, rB4[q].z));
        rB4[q].w = fmaf(w1a, a0.w, fmaf(w1b, a1.w, rB4[q].w));
        rW4[q].x = fmaf(mia, b0.x, fmaf(mib, b1.x, rW4[q].x));
        rW4[q].y = fmaf(mia, b0.y, fmaf(mib, b1.y, rW4[q].y));
        rW4[q].z = fmaf(mia, b0.z, fmaf(mib, b1.z, rW4[q].z));
        rW4[q].w = fmaf(mia, b0.w, fmaf(mib, b1.w, rW4[q].w));
      }
    }
  } else if (wave == 4) {
    float f[4];
#pragma unroll
    for (int j = 0; j < 4; ++j) {
      int row = 4 * bid + j;
      float acc = p_in_w[(size_t)row * 64 + lane] * mu[lane];
      acc = wred(acc);
      f[j] = lrelu(acc + p_in_b[row]);
    }
    if (lane == 0) {
      i4 c0; c0.x = f2i(f[0]); c0.y = f2i(f[1]); c0.z = 0; c0.w = 1;
      i4 c1; c1.x = f2i(f[2]); c1.y = f2i(f[3]); c1.z = 0; c1.w = 1;
      store16(smC + 2 * bid, c0); store16(smC + 2 * bid + 1, c1);
    }
  }

  // ---- P1: f2 = lrelu(p_h0_w f1 + b)
  { i4 v = poll16(smC + tid, 1); sX[2 * tid] = i2f(v.x); sX[2 * tid + 1] = i2f(v.y); }
  __syncthreads();
  if (wave < 4) {
    const float* w = p_h0_w + (size_t)r * 1024 + 4 * lane;
    float acc = 0.f;
#pragma unroll
    for (int q = 0; q < 4; ++q) {
      float4 wf = *(const float4*)(w + 256 * q);
      float4 xf = *(const float4*)(sX + 4 * lane + 256 * q);
      acc = fmaf(wf.x, xf.x, acc); acc = fmaf(wf.y, xf.y, acc);
      acc = fmaf(wf.z, xf.z, acc); acc = fmaf(wf.w, xf.w, acc);
    }
    acc = wred(acc);
    if (lane == 0) shF[wave] = lrelu(acc + p_h0_b[r]);
  }
  __syncthreads();
  if (tid == 0) {
    i4 c0; c0.x = f2i(shF[0]); c0.y = f2i(shF[1]); c0.z = 0; c0.w = 1;
    i4 c1; c1.x = f2i(shF[2]); c1.y = f2i(shF[3]); c1.z = 0; c1.w = 1;
    store16(cCh + 2 * bid, c0); store16(cCh + 2 * bid + 1, c1);
  }

  // ---- P2: f3 = lrelu(p_h1_w f2 + b)
  { i4 v = poll16(cCh + tid, 1); sX[2 * tid] = i2f(v.x); sX[2 * tid + 1] = i2f(v.y); }
  __syncthreads();
  if (wave < 4) {
    const float* w = p_h1_w + (size_t)r * 1024 + 4 * lane;
    float acc = 0.f;
#pragma unroll
    for (int q = 0; q < 4; ++q) {
      float4 wf = *(const float4*)(w + 256 * q);
      float4 xf = *(const float4*)(sX + 4 * lane + 256 * q);
      acc = fmaf(wf.x, xf.x, acc); acc = fmaf(wf.y, xf.y, acc);
      acc = fmaf(wf.z, xf.z, acc); acc = fmaf(wf.w, xf.w, acc);
    }
    acc = wred(acc);
    if (lane == 0) shF[wave] = lrelu(acc + p_h1_b[r]);
  }
  __syncthreads();
  if (tid == 0) {
    i4 c0; c0.x = f2i(shF[0]); c0.y = f2i(shF[1]); c0.z = 0; c0.w = 1;
    i4 c1; c1.x = f2i(shF[2]); c1.y = f2i(shF[3]); c1.z = 0; c1.w = 1;
    store16(dCh + 2 * bid, c0); store16(dCh + 2 * bid + 1, c1);
  }

  // ---- P3: z_minus = p_out_w f3 + b -> zmC + Z[0];  Z[1] = z0
  { i4 v = poll16(dCh + tid, 1); sX[2 * tid] = i2f(v.x); sX[2 * tid + 1] = i2f(v.y); }
  __syncthreads();
  if (wave < 4) {
    const float* w = p_out_w + (size_t)r * 1024 + 4 * lane;
    float acc = 0.f;
#pragma unroll
    for (int q = 0; q < 4; ++q) {
      float4 wf = *(const float4*)(w + 256 * q);
      float4 xf = *(const float4*)(sX + 4 * lane + 256 * q);
      acc = fmaf(wf.x, xf.x, acc); acc = fmaf(wf.y, xf.y, acc);
      acc = fmaf(wf.z, xf.z, acc); acc = fmaf(wf.w, xf.w, acc);
    }
    acc = wred(acc);
    if (lane == 0) shF[wave] = acc + p_out_b[r];
  }
  __syncthreads();
  if (tid == 0) {
    i4 c0; c0.x = f2i(shF[0]); c0.y = f2i(shF[1]); c0.z = 0; c0.w = 1;
    i4 c1; c1.x = f2i(shF[2]); c1.y = f2i(shF[3]); c1.z = 0; c1.w = 1;
    store16(zmC + 2 * bid, c0); store16(zmC + 2 * bid + 1, c1);
    *(float4*)(Z + 4 * bid) = make_float4(shF[0], shF[1], shF[2], shF[3]);
  }
  if (bid < 2) Z[1024 + bid * 512 + tid] = z0[bid * 512 + tid];

  // ---- P4: append row 0 (d_0 scaled -> dCc, U_0 -> sU)
  { i4 v = poll16(zmC + tid, 1); sZ[2 * tid] = i2f(v.x); sZ[2 * tid + 1] = i2f(v.y); }
  __syncthreads();
  if (wave < 4) {
    float aD = 0.f, aU = 0.f;
#pragma unroll
    for (int q = 0; q < 4; ++q) {
      float4 zf = *(const float4*)(sZ + 4 * lane + 256 * q);
      aD = fmaf(rB4[q].x, zf.x, aD); aD = fmaf(rB4[q].y, zf.y, aD);
      aD = fmaf(rB4[q].z, zf.z, aD); aD = fmaf(rB4[q].w, zf.w, aD);
      aU = fmaf(rW4[q].x, zf.x, aU); aU = fmaf(rW4[q].y, zf.y, aU);
      aU = fmaf(rW4[q].z, zf.z, aU); aU = fmaf(rW4[q].w, zf.w, aU);
    }
    wred2(aD, aU);
    if (lane == 0) { astore(dCc + r, aD * 0.03125f); sU[wave][0] = aU; }
  }
  gsync1(bar, bid, tid, lane);    // only barrier: dC row 0 cross-block writes

  float zprev_e = 0.f, mob = 0.f;
  if (wave < 4) { zprev_e = z0[r]; mob = m_out_b[r]; }

  // ---- main recurrence (pure dataflow)
  for (int t = 2; t <= 256; ++t) {
    // ---------- Phase A ----------
    if (t == 2) {
      *(float2*)(sZ + 2 * tid) = *(const float2*)(z0 + 2 * tid);
    } else {
      i4 v = poll16(eCh + tid, t - 1);
      sZ[2 * tid] = i2f(v.x); sZ[2 * tid + 1] = i2f(v.y);
    }
    __syncthreads();
    if (wave < 4) {
      float aD = 0.f, aU = 0.f;
#pragma unroll
      for (int q = 0; q < 4; ++q) {
        float4 zf = *(const float4*)(sZ + 4 * lane + 256 * q);
        aD = fmaf(rB4[q].x, zf.x, aD); aD = fmaf(rB4[q].y, zf.y, aD);
        aD = fmaf(rB4[q].z, zf.z, aD); aD = fmaf(rB4[q].w, zf.w, aD);
        aU = fmaf(rW4[q].x, zf.x, aU); aU = fmaf(rW4[q].y, zf.y, aU);
        aU = fmaf(rW4[q].z, zf.z, aU); aU = fmaf(rW4[q].w, zf.w, aU);
      }
      wred2(aD, aU);
      if (lane == 0) {
        float dsc = aD * 0.03125f;
        astore(dCc + (size_t)(t - 1) * 1024 + r, dsc);
        sU[wave][t - 1] = aU;
        shW[wave] = dsc * sZ[r];
      }
    } else {
      float part = 0.f;
      if (bid <= t - 2) {   // guard: never touch unwritten dCc lines
        const float* dr = dCc + (size_t)bid * 1024 + 256 * (wave - 4) + 4 * lane;
        float4 d4 = *(const float4*)dr;
        const float* zz = sZ + 256 * (wave - 4) + 4 * lane;
        part = d4.x * zz[0] + d4.y * zz[1] + d4.z * zz[2] + d4.w * zz[3];
      }
      part = wred(part);
      if (lane == 0) shQ[wave - 4] = part;
    }
    __builtin_amdgcn_s_waitcnt(0);    // drain dCc stores before evidencing chunk
    __syncthreads();
    if (tid == 0) {
      i4 c; c.x = f2i(shQ[0] + shQ[1] + shQ[2] + shQ[3]);
      c.y = f2i(shW[0] + shW[1] + shW[2] + shW[3]); c.z = 0; c.w = t;
      store16(aC + bid, c);
    }

    // ---------- Phase SM ----------
    if (tid < 256) {
      i4 v = poll16(aC + tid, t);
      sLg[tid] = i2f(v.x); sLp[tid] = i2f(v.y);
    }
    __syncthreads();
    float p = (tid < 256) ? sLp[tid] : 0.f;
    if (wave < 4) { p = wred(p); if (lane == 0) shW[wave] = p; }
    __syncthreads();
    {
      float newl = shW[0] + shW[1] + shW[2] + shW[3];
      float l = -1e30f;
      if (tid <= t - 2) l = sLg[tid];
      if (tid == t - 1) l = newl;
      float mx = wmax(l);
      if (lane == 0 && wave < 4) shQ[wave] = mx;
      __syncthreads();
      float m = fmaxf(fmaxf(fmaxf(shQ[0], shQ[1]), fmaxf(shQ[2], shQ[3])), 0.f);
      float e = (tid <= t - 1) ? __expf(l - m) : 0.f;
      float es = wred(e);
      if (lane == 0 && wave < 4) shS[wave] = es;
      __syncthreads();
      float den = shS[0] + shS[1] + shS[2] + shS[3] + (float)(257 - t) * __expf(-m);
      if (tid < 256) sR[tid] = e / den;
    }
    __syncthreads();
    if (wave < 4) {
      float acc = 0.f;
#pragma unroll
      for (int j = 0; j < 4; ++j) {
        int i = lane + 64 * j;
        if (i <= t - 1) acc = fmaf(sR[i], sU[wave][i], acc);
      }
      acc = wred(acc);
      if (lane == 0) shF[wave] = lrelu(acc + m_in_b[r]);
    }
    __syncthreads();
    if (tid == 0) {
      i4 c0; c0.x = f2i(shF[0]); c0.y = f2i(shF[1]); c0.z = 0; c0.w = t;
      i4 c1; c1.x = f2i(shF[2]); c1.y = f2i(shF[3]); c1.z = 0; c1.w = t;
      store16(smC + 2 * bid, c0); store16(smC + 2 * bid + 1, c1);
    }

    // ---------- Phase C ----------
    { i4 v = poll16(smC + tid, t); sX[2 * tid] = i2f(v.x); sX[2 * tid + 1] = i2f(v.y); }
    __syncthreads();
    if (wave < 4) {
      const float* w = m_h0_w + (size_t)r * 1024 + 4 * lane;
      float acc = 0.f;
#pragma unroll
      for (int q = 0; q < 4; ++q) {
        float4 wf = *(const float4*)(w + 256 * q);
        float4 xf = *(const float4*)(sX + 4 * lane + 256 * q);
        acc = fmaf(wf.x, xf.x, acc); acc = fmaf(wf.y, xf.y, acc);
        acc = fmaf(wf.z, xf.z, acc); acc = fmaf(wf.w, xf.w, acc);
      }
      acc = wred(acc);
      if (lane == 0) shF[wave] = lrelu(acc + m_h0_b[r]);
    }
    __syncthreads();
    if (tid == 0) {
      i4 c0; c0.x = f2i(shF[0]); c0.y = f2i(shF[1]); c0.z = 0; c0.w = t;
      i4 c1; c1.x = f2i(shF[2]); c1.y = f2i(shF[3]); c1.z = 0; c1.w = t;
      store16(cCh + 2 * bid, c0); store16(cCh + 2 * bid + 1, c1);
    }

    // ---------- Phase D ----------
    { i4 v = poll16(cCh + tid, t); sX[2 * tid] = i2f(v.x); sX[2 * tid + 1] = i2f(v.y); }
    __syncthreads();
    if (wave < 4) {
      const float* w = m_h1_w + (size_t)r * 1024 + 4 * lane;
      float acc = 0.f;
#pragma unroll
      for (int q = 0; q < 4; ++q) {
        float4 wf = *(const float4*)(w + 256 * q);
        float4 xf = *(const float4*)(sX + 4 * lane + 256 * q);
        acc = fmaf(wf.x, xf.x, acc); acc = fmaf(wf.y, xf.y, acc);
        acc = fmaf(wf.z, xf.z, acc); acc = fmaf(wf.w, xf.w, acc);
      }
      acc = wred(acc);
      if (lane == 0) shF[wave] = lrelu(acc + m_h1_b[r]);
    }
    __syncthreads();
    if (tid == 0) {
      i4 c0; c0.x = f2i(shF[0]); c0.y = f2i(shF[1]); c0.z = 0; c0.w = t;
      i4 c1; c1.x = f2i(shF[2]); c1.y = f2i(shF[3]); c1.z = 0; c1.w = t;
      store16(dCh + 2 * bid, c0); store16(dCh + 2 * bid + 1, c1);
    }

    // ---------- Phase E ----------
    { i4 v = poll16(dCh + tid, t); sX[2 * tid] = i2f(v.x); sX[2 * tid + 1] = i2f(v.y); }
    __syncthreads();
    if (wave < 4) {
      const float* w = m_out_w + (size_t)r * 1024 + 4 * lane;
      float acc = 0.f;
#pragma unroll
      for (int q = 0; q < 4; ++q) {
        float4 wf = *(const float4*)(w + 256 * q);
        float4 xf = *(const float4*)(sX + 4 * lane + 256 * q);
        acc = fmaf(wf.x, xf.x, acc); acc = fmaf(wf.y, xf.y, acc);
        acc = fmaf(wf.z, xf.z, acc); acc = fmaf(wf.w, xf.w, acc);
      }
      acc = wred(acc);
      float znew = zprev_e + acc + mob;
      zprev_e = znew;
      if (lane == 0) shF[wave] = znew;
    }
    __syncthreads();
    if (tid == 0) {
      i4 c0; c0.x = f2i(shF[0]); c0.y = f2i(shF[1]); c0.z = 0; c0.w = t;
      i4 c1; c1.x = f2i(shF[2]); c1.y = f2i(shF[3]); c1.z = 0; c1.w = t;
      store16(eCh + 2 * bid, c0); store16(eCh + 2 * bid + 1, c1);
      *(float4*)(Z + (size_t)t * 1024 + 4 * bid) =
          make_float4(shF[0], shF[1], shF[2], shF[3]);
    }
  }
}

extern "C" void kernel_launch(void* const* d_in, const int* in_sizes, int n_in,
                              void* d_out, int out_size, void* d_ws, size_t ws_size,
                              hipStream_t stream) {
  (void)in_sizes; (void)n_in; (void)out_size; (void)ws_size;
  hipMemsetAsync(d_ws, 0, 49152, stream);  // barrier counters + all chunk tags
  tcell<<<dim3(NBLK), dim3(NTHR), 0, stream>>>(
      (const float*)d_in[0],  (const float*)d_in[1],
      (const float*)d_in[2],  (const float*)d_in[3],  (const float*)d_in[4],
      (const float*)d_in[5],  (const float*)d_in[6],
      (const float*)d_in[7],  (const float*)d_in[8],
      (const float*)d_in[9],  (const float*)d_in[10],
      (const float*)d_in[11], (const float*)d_in[12],
      (const float*)d_in[13], (const float*)d_in[14],
      (const float*)d_in[15], (const float*)d_in[16],
      (const float*)d_in[17], (const float*)d_in[18],
      (const float*)d_in[19], (const float*)d_in[20],
      (float*)d_out, (float*)d_ws);
}

// Round 9
// 3297.606 us; speedup vs baseline: 3.2751x; 1.2645x over previous
//
#include <hip/hip_runtime.h>
#include <math.h>

// TransformerCell — flag-fused dataflow + x8 replica de-contention.
// 256 blocks x 512 threads, no global barriers in the main loop.
// Each phase output: 16B chunks {payload2, pad, tag}, stored with ONE
// global_store_dwordx4 sc0 sc1 per replica (8 replicas, lanes 0-15 fire in
// parallel). Consumers poll replica (bid&7): sync+data = one LLC trip,
// ~128 pollers/line instead of 1024.
// Phases/step: A (append d/U, logits -> aC) -> SM (1-wave softmax + f1 -> smC)
// -> C (f2 -> cCh) -> D (f3 -> dCh) -> E (z -> eCh + Z row).
// Overwrite safety: transitive dataflow chain covers all replicas (any
// rewrite at t+1 is ordered behind every block's consumption at t).
// dCc: agent-store once, waitcnt-drained before the evidencing aC store,
// normal-cached-read by its single reader strictly afterwards.
// Tags reset per launch by memset (356KB+bar) => replay-deterministic.

#define NTHR 512
#define NBLK 256

// byte offsets in ws
#define B_AC  4096     /* aC  [8][256] chunks */
#define B_SM  36864    /* smC [8][512] */
#define B_C   102400   /* cCh [8][512] */
#define B_D   167936   /* dCh [8][512] */
#define B_E   233472   /* eCh [8][512] */
#define B_ZM  299008   /* zmC [8][512] */
#define B_DCC 364544   /* dCc float[257][1024], pre-scaled 1/32 */

typedef int i4 __attribute__((ext_vector_type(4)));

__device__ __forceinline__ float i2f(int x) { return __int_as_float(x); }
__device__ __forceinline__ int f2i(float x) { return __float_as_int(x); }

__device__ __forceinline__ void astore(float* p, float v) {
  __hip_atomic_store(p, v, __ATOMIC_RELAXED, __HIP_MEMORY_SCOPE_AGENT);
}
__device__ __forceinline__ int aloadI(const int* p) {
  return __hip_atomic_load((int*)p, __ATOMIC_RELAXED, __HIP_MEMORY_SCOPE_AGENT);
}
__device__ __forceinline__ int afaddI(int* p) {
  return __hip_atomic_fetch_add(p, 1, __ATOMIC_RELAXED, __HIP_MEMORY_SCOPE_AGENT);
}

__device__ __forceinline__ i4 poll16(const i4* p, int tag) {
  i4 v;
  for (;;) {
    asm volatile("global_load_dwordx4 %0, %1, off sc0 sc1\n\ts_waitcnt vmcnt(0)"
                 : "=&v"(v) : "v"(p) : "memory");
    if (v.w == tag) return v;
    __builtin_amdgcn_s_sleep(1);
  }
}
__device__ __forceinline__ void store16(i4* p, i4 v) {
  asm volatile("global_store_dwordx4 %0, %1, off sc0 sc1" :: "v"(p), "v"(v) : "memory");
}

__device__ __forceinline__ float wred(float v) {
#pragma unroll
  for (int o = 1; o < 64; o <<= 1) v += __shfl_xor(v, o, 64);
  return v;
}
__device__ __forceinline__ void wred2(float& a, float& b) {
#pragma unroll
  for (int o = 1; o < 64; o <<= 1) { a += __shfl_xor(a, o, 64); b += __shfl_xor(b, o, 64); }
}
__device__ __forceinline__ float wmax(float v) {
#pragma unroll
  for (int o = 1; o < 64; o <<= 1) v = fmaxf(v, __shfl_xor(v, o, 64));
  return v;
}
__device__ __forceinline__ float lrelu(float x) { return x > 0.f ? x : 0.01f * x; }

__device__ __forceinline__ void gsync1(int* bar, int bid, int tid, int lane) {
  asm volatile("" ::: "memory");
  __builtin_amdgcn_s_waitcnt(0);
  __syncthreads();
  if (tid == 0) afaddI(bar + (bid & 7) * 16);
  if (tid < 64) {
    for (;;) {
      int v = (lane < 8) ? aloadI(bar + lane * 16) : 0x7fffffff;
      if (__all(v >= 32)) break;
      __builtin_amdgcn_s_sleep(2);
    }
  }
  __syncthreads();
  asm volatile("" ::: "memory");
}

__global__ void __launch_bounds__(NTHR) tcell(
    const float* __restrict__ mu, const float* __restrict__ z0,
    const float* __restrict__ W1, const float* __restrict__ W2, const float* __restrict__ W3,
    const float* __restrict__ p_in_w, const float* __restrict__ p_in_b,
    const float* __restrict__ p_h0_w, const float* __restrict__ p_h0_b,
    const float* __restrict__ p_h1_w, const float* __restrict__ p_h1_b,
    const float* __restrict__ p_out_w, const float* __restrict__ p_out_b,
    const float* __restrict__ m_in_w, const float* __restrict__ m_in_b,
    const float* __restrict__ m_h0_w, const float* __restrict__ m_h0_b,
    const float* __restrict__ m_h1_w, const float* __restrict__ m_h1_b,
    const float* __restrict__ m_out_w, const float* __restrict__ m_out_b,
    float* __restrict__ Z, float* __restrict__ ws) {
  const int tid = threadIdx.x;
  const int bid = blockIdx.x;
  const int lane = tid & 63;
  const int wave = tid >> 6;            // 0..7
  const int r = 4 * bid + (wave & 3);
  const int rep = bid & 7;

  char* wsb = (char*)ws;
  int* bar = (int*)wsb;
  i4* aC  = (i4*)(wsb + B_AC);
  i4* smC = (i4*)(wsb + B_SM);
  i4* cCh = (i4*)(wsb + B_C);
  i4* dCh = (i4*)(wsb + B_D);
  i4* eCh = (i4*)(wsb + B_E);
  i4* zmC = (i4*)(wsb + B_ZM);
  float* dCc = (float*)(wsb + B_DCC);
  // consumer replica views
  i4* aCr  = aC  + rep * 256;
  i4* smCr = smC + rep * 512;
  i4* cChr = cCh + rep * 512;
  i4* dChr = dCh + rep * 512;
  i4* eChr = eCh + rep * 512;
  i4* zmCr = zmC + rep * 512;

  __shared__ float sZ[1024], sX[1024];
  __shared__ float sR[256], sLg[256], sLp[256];
  __shared__ float sU[4][257];
  __shared__ float shW[4], shQ[4], shF[4];

  // ---- P0: waves 0-3 build B=W1@W2, W~=m_in_w@W3 rows (regs); wave 4: p_in
  float4 rB4[4], rW4[4];
  if (wave < 4) {
#pragma unroll
    for (int q = 0; q < 4; ++q) {
      rB4[q] = make_float4(0.f, 0.f, 0.f, 0.f);
      rW4[q] = make_float4(0.f, 0.f, 0.f, 0.f);
    }
    const float* __restrict__ w1r = W1 + (size_t)r * 512;
    const float* __restrict__ mir = m_in_w + (size_t)r * 512;
    for (int k = 0; k < 512; k += 2) {
      float w1a = w1r[k], w1b = w1r[k + 1];
      float mia = mir[k], mib = mir[k + 1];
      const float* w2a = W2 + (size_t)k * 1024 + 4 * lane;
      const float* w3a = W3 + (size_t)k * 1024 + 4 * lane;
#pragma unroll
      for (int q = 0; q < 4; ++q) {
        float4 a0 = *(const float4*)(w2a + 256 * q);
        float4 a1 = *(const float4*)(w2a + 1024 + 256 * q);
        float4 b0 = *(const float4*)(w3a + 256 * q);
        float4 b1 = *(const float4*)(w3a + 1024 + 256 * q);
        rB4[q].x = fmaf(w1a, a0.x, fmaf(w1b, a1.x, rB4[q].x));
        rB4[q].y = fmaf(w1a, a0.y, fmaf(w1b, a1.y, rB4[q].y));
        rB4[q].z = fmaf(w1a, a0.z, fmaf(w1b, a1.z, rB4[q].z));
        rB4[q].w = fmaf(w1a, a0.w, fmaf(w1b, a1.w, rB4[q].w));
        rW4[q].x = fmaf(mia, b0.x, fmaf(mib, b1.x, rW4[q].x));
        rW4[q].y = fmaf(mia, b0.y, fmaf(mib, b1.y, rW4[q].y));
        rW4[q].z = fmaf(mia, b0.z, fmaf(mib, b1.z, rW4[q].z));
        rW4[q].w = fmaf(mia, b0.w, fmaf(mib, b1.w, rW4[q].w));
      }
    }
  } else if (wave == 4) {
    float f[4];
#pragma unroll
    for (int j = 0; j < 4; ++j) {
      int row = 4 * bid + j;
      float acc = p_in_w[(size_t)row * 64 + lane] * mu[lane];
      acc = wred(acc);
      f[j] = lrelu(acc + p_in_b[row]);   // all lanes hold all 4 after wred
    }
    if (lane < 16) {
      int rp = lane >> 1, ch = lane & 1;
      i4 c; c.x = f2i(f[2 * ch]); c.y = f2i(f[2 * ch + 1]); c.z = 0; c.w = 1;
      store16(smC + rp * 512 + 2 * bid + ch, c);
    }
  }

#define MV_PHASE(WPTR, BPTR, ACT, OUTC, TAG)                                   \
  if (wave < 4) {                                                              \
    const float* w = (WPTR) + (size_t)r * 1024 + 4 * lane;                     \
    float acc = 0.f;                                                           \
    _Pragma("unroll")                                                          \
    for (int q = 0; q < 4; ++q) {                                              \
      float4 wf = *(const float4*)(w + 256 * q);                               \
      float4 xf = *(const float4*)(sX + 4 * lane + 256 * q);                   \
      acc = fmaf(wf.x, xf.x, acc); acc = fmaf(wf.y, xf.y, acc);                \
      acc = fmaf(wf.z, xf.z, acc); acc = fmaf(wf.w, xf.w, acc);                \
    }                                                                          \
    acc = wred(acc);                                                           \
    if (lane == 0) shF[wave] = (ACT) ? lrelu(acc + (BPTR)[r]) : (acc + (BPTR)[r]); \
  }                                                                            \
  __syncthreads();                                                             \
  if (tid < 16) {                                                              \
    int rp = tid >> 1, ch = tid & 1;                                           \
    i4 c; c.x = f2i(shF[2 * ch]); c.y = f2i(shF[2 * ch + 1]); c.z = 0; c.w = (TAG); \
    store16((OUTC) + rp * 512 + 2 * bid + ch, c);                              \
  }

  // ---- P1: f2 = lrelu(p_h0_w f1 + b)
  { i4 v = poll16(smCr + tid, 1); sX[2 * tid] = i2f(v.x); sX[2 * tid + 1] = i2f(v.y); }
  __syncthreads();
  MV_PHASE(p_h0_w, p_h0_b, 1, cCh, 1)

  // ---- P2: f3 = lrelu(p_h1_w f2 + b)
  { i4 v = poll16(cChr + tid, 1); sX[2 * tid] = i2f(v.x); sX[2 * tid + 1] = i2f(v.y); }
  __syncthreads();
  MV_PHASE(p_h1_w, p_h1_b, 1, dCh, 1)

  // ---- P3: z_minus -> zmC + Z[0]; Z[1] = z0
  { i4 v = poll16(dChr + tid, 1); sX[2 * tid] = i2f(v.x); sX[2 * tid + 1] = i2f(v.y); }
  __syncthreads();
  MV_PHASE(p_out_w, p_out_b, 0, zmC, 1)
  if (tid == 16) *(float4*)(Z + 4 * bid) = make_float4(shF[0], shF[1], shF[2], shF[3]);
  if (bid < 2) Z[1024 + bid * 512 + tid] = z0[bid * 512 + tid];

  // ---- P4: append row 0 (d_0 scaled -> dCc, U_0 -> sU)
  { i4 v = poll16(zmCr + tid, 1); sZ[2 * tid] = i2f(v.x); sZ[2 * tid + 1] = i2f(v.y); }
  __syncthreads();
  if (wave < 4) {
    float aD = 0.f, aU = 0.f;
#pragma unroll
    for (int q = 0; q < 4; ++q) {
      float4 zf = *(const float4*)(sZ + 4 * lane + 256 * q);
      aD = fmaf(rB4[q].x, zf.x, aD); aD = fmaf(rB4[q].y, zf.y, aD);
      aD = fmaf(rB4[q].z, zf.z, aD); aD = fmaf(rB4[q].w, zf.w, aD);
      aU = fmaf(rW4[q].x, zf.x, aU); aU = fmaf(rW4[q].y, zf.y, aU);
      aU = fmaf(rW4[q].z, zf.z, aU); aU = fmaf(rW4[q].w, zf.w, aU);
    }
    wred2(aD, aU);
    if (lane == 0) { astore(dCc + r, aD * 0.03125f); sU[wave][0] = aU; }
  }
  gsync1(bar, bid, tid, lane);    // only barrier: dCc row-0 cross-block writes

  float zprev_e = 0.f, mob = 0.f;
  if (wave < 4) { zprev_e = z0[r]; mob = m_out_b[r]; }

  // ---- main recurrence (pure dataflow)
  for (int t = 2; t <= 256; ++t) {
    // ---------- Phase A ----------
    if (t == 2) {
      *(float2*)(sZ + 2 * tid) = *(const float2*)(z0 + 2 * tid);
    } else {
      i4 v = poll16(eChr + tid, t - 1);
      sZ[2 * tid] = i2f(v.x); sZ[2 * tid + 1] = i2f(v.y);
    }
    __syncthreads();
    if (wave < 4) {
      float aD = 0.f, aU = 0.f;
#pragma unroll
      for (int q = 0; q < 4; ++q) {
        float4 zf = *(const float4*)(sZ + 4 * lane + 256 * q);
        aD = fmaf(rB4[q].x, zf.x, aD); aD = fmaf(rB4[q].y, zf.y, aD);
        aD = fmaf(rB4[q].z, zf.z, aD); aD = fmaf(rB4[q].w, zf.w, aD);
        aU = fmaf(rW4[q].x, zf.x, aU); aU = fmaf(rW4[q].y, zf.y, aU);
        aU = fmaf(rW4[q].z, zf.z, aU); aU = fmaf(rW4[q].w, zf.w, aU);
      }
      wred2(aD, aU);
      if (lane == 0) {
        float dsc = aD * 0.03125f;
        astore(dCc + (size_t)(t - 1) * 1024 + r, dsc);
        sU[wave][t - 1] = aU;
        shW[wave] = dsc * sZ[r];
      }
    } else {
      float part = 0.f;
      if (bid <= t - 2) {
        const float* dr = dCc + (size_t)bid * 1024 + 256 * (wave - 4) + 4 * lane;
        float4 d4 = *(const float4*)dr;
        const float* zz = sZ + 256 * (wave - 4) + 4 * lane;
        part = d4.x * zz[0] + d4.y * zz[1] + d4.z * zz[2] + d4.w * zz[3];
      }
      part = wred(part);
      if (lane == 0) shQ[wave - 4] = part;
    }
    __builtin_amdgcn_s_waitcnt(0);    // drain dCc stores before evidencing chunk
    __syncthreads();
    if (tid < 8) {
      i4 c; c.x = f2i(shQ[0] + shQ[1] + shQ[2] + shQ[3]);
      c.y = f2i(shW[0] + shW[1] + shW[2] + shW[3]); c.z = 0; c.w = t;
      store16(aC + tid * 256 + bid, c);
    }

    // ---------- Phase SM (single-wave softmax) ----------
    if (tid < 256) {
      i4 v = poll16(aCr + tid, t);
      sLg[tid] = i2f(v.x); sLp[tid] = i2f(v.y);
    }
    __syncthreads();
    if (wave == 0) {
      float p = sLp[lane] + sLp[lane + 64] + sLp[lane + 128] + sLp[lane + 192];
      p = wred(p);                      // new-row logit (pre-scaled)
      float l[4]; float mx = -1e30f;
#pragma unroll
      for (int j = 0; j < 4; ++j) {
        int i = lane + 64 * j;
        float li = (i <= t - 2) ? sLg[i] : ((i == t - 1) ? p : -1e30f);
        l[j] = li; mx = fmaxf(mx, li);
      }
      mx = wmax(mx);
      float m = fmaxf(mx, 0.f);
      float e[4], es = 0.f;
#pragma unroll
      for (int j = 0; j < 4; ++j) {
        int i = lane + 64 * j;
        e[j] = (i <= t - 1) ? __expf(l[j] - m) : 0.f;
        es += e[j];
      }
      es = wred(es);
      float inv = 1.f / (es + (float)(257 - t) * __expf(-m));
#pragma unroll
      for (int j = 0; j < 4; ++j) sR[lane + 64 * j] = e[j] * inv;
    }
    __syncthreads();
    if (wave < 4) {
      float acc = 0.f;
#pragma unroll
      for (int j = 0; j < 4; ++j) {
        int i = lane + 64 * j;
        if (i <= t - 1) acc = fmaf(sR[i], sU[wave][i], acc);
      }
      acc = wred(acc);
      if (lane == 0) shF[wave] = lrelu(acc + m_in_b[r]);
    }
    __syncthreads();
    if (tid < 16) {
      int rp = tid >> 1, ch = tid & 1;
      i4 c; c.x = f2i(shF[2 * ch]); c.y = f2i(shF[2 * ch + 1]); c.z = 0; c.w = t;
      store16(smC + rp * 512 + 2 * bid + ch, c);
    }

    // ---------- Phase C ----------
    { i4 v = poll16(smCr + tid, t); sX[2 * tid] = i2f(v.x); sX[2 * tid + 1] = i2f(v.y); }
    __syncthreads();
    MV_PHASE(m_h0_w, m_h0_b, 1, cCh, t)

    // ---------- Phase D ----------
    { i4 v = poll16(cChr + tid, t); sX[2 * tid] = i2f(v.x); sX[2 * tid + 1] = i2f(v.y); }
    __syncthreads();
    MV_PHASE(m_h1_w, m_h1_b, 1, dCh, t)

    // ---------- Phase E ----------
    { i4 v = poll16(dChr + tid, t); sX[2 * tid] = i2f(v.x); sX[2 * tid + 1] = i2f(v.y); }
    __syncthreads();
    if (wave < 4) {
      const float* w = m_out_w + (size_t)r * 1024 + 4 * lane;
      float acc = 0.f;
#pragma unroll
      for (int q = 0; q < 4; ++q) {
        float4 wf = *(const float4*)(w + 256 * q);
        float4 xf = *(const float4*)(sX + 4 * lane + 256 * q);
        acc = fmaf(wf.x, xf.x, acc); acc = fmaf(wf.y, xf.y, acc);
        acc = fmaf(wf.z, xf.z, acc); acc = fmaf(wf.w, xf.w, acc);
      }
      acc = wred(acc);
      float znew = zprev_e + acc + mob;
      zprev_e = znew;
      if (lane == 0) shF[wave] = znew;
    }
    __syncthreads();
    if (tid < 16) {
      int rp = tid >> 1, ch = tid & 1;
      i4 c; c.x = f2i(shF[2 * ch]); c.y = f2i(shF[2 * ch + 1]); c.z = 0; c.w = t;
      store16(eCh + rp * 512 + 2 * bid + ch, c);
    }
    if (tid == 16)
      *(float4*)(Z + (size_t)t * 1024 + 4 * bid) =
          make_float4(shF[0], shF[1], shF[2], shF[3]);
  }
}

extern "C" void kernel_launch(void* const* d_in, const int* in_sizes, int n_in,
                              void* d_out, int out_size, void* d_ws, size_t ws_size,
                              hipStream_t stream) {
  (void)in_sizes; (void)n_in; (void)out_size; (void)ws_size;
  hipMemsetAsync(d_ws, 0, 364544, stream);  // barrier + all replica chunk tags
  tcell<<<dim3(NBLK), dim3(NTHR), 0, stream>>>(
      (const float*)d_in[0],  (const float*)d_in[1],
      (const float*)d_in[2],  (const float*)d_in[3],  (const float*)d_in[4],
      (const float*)d_in[5],  (const float*)d_in[6],
      (const float*)d_in[7],  (const float*)d_in[8],
      (const float*)d_in[9],  (const float*)d_in[10],
      (const float*)d_in[11], (const float*)d_in[12],
      (const float*)d_in[13], (const float*)d_in[14],
      (const float*)d_in[15], (const float*)d_in[16],
      (const float*)d_in[17], (const float*)d_in[18],
      (const float*)d_in[19], (const float*)d_in[20],
      (float*)d_out, (float*)d_ws);
}